// Round 1
// baseline (607.120 us; speedup 1.0000x reference)
//
#include <hip/hip_runtime.h>

// Problem constants (from reference setup_inputs)
// B=8, C=v_in=v_out=128, S=s_in=s_out=64, N=4096, D=3
#define TS 16          // sites (n-values) per block
#define VOUT_ELEMS 12582912   // 8*128*3*4096

// ws float layout
#define OFF_W1T   0
#define OFF_W2T   16384
#define OFF_WFCAT 32768
#define OFF_WFCBT 49152
#define OFF_VDIRT 65536
#define OFF_SVT   81920
#define OFF_VST   90112
#define OFF_SST   98304
#define OFF_B2N   102400
#define OFF_BFCN  102528
#define OFF_BDIRN 102656

__device__ __forceinline__ float grp_sum(float v) {
#pragma unroll
  for (int m = 16; m; m >>= 1) v += __shfl_xor(v, m, 64);
  return v;
}

// ---------------- prep: completed + transposed weights, normalized eps-biases ----------------
__global__ void kprep(const float* __restrict__ weight,
                      const float* __restrict__ cross_w, const float* __restrict__ cross_b,
                      const float* __restrict__ crossfc_w, const float* __restrict__ crossfc_b,
                      const float* __restrict__ vsdir_w, const float* __restrict__ vsdir_b,
                      const float* __restrict__ sv_w, const float* __restrict__ vs_w,
                      const float* __restrict__ ss_w,
                      float* __restrict__ ws)
{
  const int o = threadIdx.x;  // 128 threads
  float* W1t   = ws + OFF_W1T;
  float* W2t   = ws + OFF_W2T;
  float* WfcAt = ws + OFF_WFCAT;
  float* WfcBt = ws + OFF_WFCBT;
  float* Vdirt = ws + OFF_VDIRT;
  float* SVt   = ws + OFF_SVT;
  float* VSt   = ws + OFF_VST;
  float* SSt   = ws + OFF_SST;
  float* b2n   = ws + OFF_B2N;
  float* bfcn  = ws + OFF_BFCN;
  float* bdirn = ws + OFF_BDIRN;

  // W1 = se3 completion of weight [128,127] -> [128,128], stored transposed [c][o]
  float rs = 0.f;
  for (int c = 0; c < 127; ++c) { float w = weight[o*127+c]; rs += w; W1t[c*128+o] = w; }
  W1t[127*128+o] = 1.f - rs;

  rs = 0.f;
  for (int c = 0; c < 127; ++c) { float w = cross_w[o*127+c]; rs += w; W2t[c*128+o] = w; }
  W2t[127*128+o] = 1.f - rs;

  // Wfc = se3 completion of crossfc_w [128,255] -> [128,256], split in halves, transposed
  rs = 0.f;
  for (int c = 0; c < 255; ++c) rs += crossfc_w[o*255+c];
  for (int c = 0; c < 128; ++c) WfcAt[c*128+o] = crossfc_w[o*255+c];
  for (int c = 0; c < 127; ++c) WfcBt[c*128+o] = crossfc_w[o*255+128+c];
  WfcBt[127*128+o] = 1.f - rs;

  for (int c = 0; c < 128; ++c) Vdirt[c*128+o] = vsdir_w[o*128+c];
  for (int s = 0; s < 64; ++s)  SVt[s*128+o]   = sv_w[o*64+s];
  if (o < 64) {
    for (int c = 0; c < 128; ++c) VSt[c*64+o] = vs_w[o*128+c];
    for (int s = 0; s < 64; ++s)  SSt[s*64+o] = ss_w[o*64+s];
  }

  __shared__ float red[128];

  // b2n = l2n(cross_b) * 1e-6
  red[o] = cross_b[o]*cross_b[o];
  __syncthreads();
  for (int st2 = 64; st2 > 0; st2 >>= 1) { if (o < st2) red[o] += red[o+st2]; __syncthreads(); }
  float nb = sqrtf(red[0]);
  __syncthreads();
  b2n[o] = cross_b[o] / fmaxf(nb, 1e-12f) * 1e-6f;

  red[o] = crossfc_b[o]*crossfc_b[o];
  __syncthreads();
  for (int st2 = 64; st2 > 0; st2 >>= 1) { if (o < st2) red[o] += red[o+st2]; __syncthreads(); }
  nb = sqrtf(red[0]);
  __syncthreads();
  bfcn[o] = crossfc_b[o] / fmaxf(nb, 1e-12f) * 1e-6f;

  red[o] = vsdir_b[o]*vsdir_b[o];
  __syncthreads();
  for (int st2 = 64; st2 > 0; st2 >>= 1) { if (o < st2) red[o] += red[o+st2]; __syncthreads(); }
  nb = sqrtf(red[0]);
  __syncthreads();
  bdirn[o] = vsdir_b[o] / fmaxf(nb, 1e-12f) * 1e-6f;
}

// matvec: acc[k][d] += sum_c Wt[c][o] * X[c][d][g],  o = l + 32k
#define MATVEC_ACC(XBUF, ACC)                                       \
  _Pragma("unroll 4")                                               \
  for (int c = 0; c < 128; ++c) {                                   \
    float x0 = XBUF[(c*3+0)*17+g];                                  \
    float x1 = XBUF[(c*3+1)*17+g];                                  \
    float x2 = XBUF[(c*3+2)*17+g];                                  \
    _Pragma("unroll")                                               \
    for (int k = 0; k < 4; ++k) {                                   \
      float w = Wt[c*128 + l + 32*k];                               \
      ACC[k][0] = fmaf(w, x0, ACC[k][0]);                           \
      ACC[k][1] = fmaf(w, x1, ACC[k][1]);                           \
      ACC[k][2] = fmaf(w, x2, ACC[k][2]);                           \
    }                                                               \
  }

#define STAGE_W(SRC, CNT)                                           \
  __syncthreads();                                                  \
  for (int i = tid; i < (CNT); i += 512) Wt[i] = (SRC)[i];          \
  __syncthreads();

// ---------------- v-branch ----------------
__global__ __launch_bounds__(512, 1) void kv_kernel(
    const float* __restrict__ v_in, const float* __restrict__ s_in,
    const float* __restrict__ sv_b, const float* __restrict__ ws,
    float* __restrict__ out_v)
{
  const int b  = blockIdx.y;
  const int n0 = blockIdx.x * TS;
  const int tid = threadIdx.x;
  const int l = tid & 31;
  const int g = tid >> 5;   // site 0..15

  const float* gW1t   = ws + OFF_W1T;
  const float* gW2t   = ws + OFF_W2T;
  const float* gWfcAt = ws + OFF_WFCAT;
  const float* gWfcBt = ws + OFF_WFCBT;
  const float* gSVt   = ws + OFF_SVT;
  const float* gb2n   = ws + OFF_B2N;
  const float* gbfcn  = ws + OFF_BFCN;

  __shared__ float Wt[16384];     // staged weight (64KB)
  __shared__ float xv[384*17];    // v tile   [row=c*3+d][site], pad 17
  __shared__ float xo[384*17];    // v_o tile
  __shared__ float xd[384*17];    // dual/cross tile
  __shared__ float st[64*TS];     // s tile [s][site]

  const size_t vbase = ((size_t)b*384)*4096 + n0;
  for (int i = tid; i < 6144; i += 512)
    xv[(i>>4)*17 + (i&15)] = v_in[vbase + (size_t)(i>>4)*4096 + (i&15)];
  const size_t sbase = ((size_t)b*64)*4096 + n0;
  for (int i = tid; i < 1024; i += 512)
    st[i] = s_in[sbase + (size_t)(i>>4)*4096 + (i&15)];

  // ---- stage 1: v_o = W1 @ v ----
  STAGE_W(gW1t, 16384);
  float vo[4][3];
#pragma unroll
  for (int k = 0; k < 4; ++k) { vo[k][0]=0.f; vo[k][1]=0.f; vo[k][2]=0.f; }
  MATVEC_ACC(xv, vo);

  float m0 = grp_sum(vo[0][0]+vo[1][0]+vo[2][0]+vo[3][0]) * (1.f/128.f);
  float m1 = grp_sum(vo[0][1]+vo[1][1]+vo[2][1]+vo[3][1]) * (1.f/128.f);
  float m2 = grp_sum(vo[0][2]+vo[1][2]+vo[2][2]+vo[3][2]) * (1.f/128.f);

  // ---- stage 2: scale = l2n(sv_w@s + sv_b) over channels ----
  STAGE_W(gSVt, 8192);
  float sc[4];
#pragma unroll
  for (int k = 0; k < 4; ++k) sc[k] = sv_b[l + 32*k];
  for (int s = 0; s < 64; ++s) {
    float xs = st[s*TS+g];
#pragma unroll
    for (int k = 0; k < 4; ++k) sc[k] = fmaf(Wt[s*128 + l + 32*k], xs, sc[k]);
  }
  float scn = grp_sum(sc[0]*sc[0]+sc[1]*sc[1]+sc[2]*sc[2]+sc[3]*sc[3]);
  float sinv = 1.f / fmaxf(sqrtf(scn), 1e-12f);

  float oo0 = 0.f, oo1 = 0.f, oo2 = 0.f;
#pragma unroll
  for (int k = 0; k < 4; ++k) {
    float s_k = sc[k] * sinv;
    float t0 = (vo[k][0]-m0)*s_k + m0;
    float t1 = (vo[k][1]-m1)*s_k + m1;
    float t2 = (vo[k][2]-m2)*s_k + m2;
    vo[k][0]=t0; vo[k][1]=t1; vo[k][2]=t2;
    oo0 += t0; oo1 += t1; oo2 += t2;
    int c = l + 32*k;
    xo[(c*3+0)*17+g]=t0; xo[(c*3+1)*17+g]=t1; xo[(c*3+2)*17+g]=t2;
  }
  oo0 = grp_sum(oo0)*(1.f/128.f);
  oo1 = grp_sum(oo1)*(1.f/128.f);
  oo2 = grp_sum(oo2)*(1.f/128.f);

  // ---- stage 3: dual = W2 @ v + eps_bias; cev-norm; cross ----
  STAGE_W(gW2t, 16384);
  float du[4][3];
#pragma unroll
  for (int k = 0; k < 4; ++k) { float bb = gb2n[l+32*k]; du[k][0]=bb; du[k][1]=bb; du[k][2]=bb; }
  MATVEC_ACC(xv, du);

  float dm0 = grp_sum(du[0][0]+du[1][0]+du[2][0]+du[3][0]) * (1.f/128.f);
  float dm1 = grp_sum(du[0][1]+du[1][1]+du[2][1]+du[3][1]) * (1.f/128.f);
  float dm2 = grp_sum(du[0][2]+du[1][2]+du[2][2]+du[3][2]) * (1.f/128.f);

  float f2loc = 0.f;
  float rn[4];
#pragma unroll
  for (int k = 0; k < 4; ++k) {
    du[k][0]-=dm0; du[k][1]-=dm1; du[k][2]-=dm2;
    float q = du[k][0]*du[k][0]+du[k][1]*du[k][1]+du[k][2]*du[k][2];
    rn[k] = sqrtf(q);
    f2loc += q;
  }
  float F = sqrtf(grp_sum(f2loc));
#pragma unroll
  for (int k = 0; k < 4; ++k) {
    float s1 = (rn[k] / fmaxf(F, 1e-12f)) / fmaxf(rn[k], 1e-12f);
    float a0 = du[k][0]*s1, a1 = du[k][1]*s1, a2 = du[k][2]*s1;
    float b0v = vo[k][0]-oo0, b1v = vo[k][1]-oo1, b2v = vo[k][2]-oo2;
    float cv0 = a1*b2v - a2*b1v + vo[k][0];
    float cv1 = a2*b0v - a0*b2v + vo[k][1];
    float cv2 = a0*b1v - a1*b0v + vo[k][2];
    int c = l + 32*k;
    xd[(c*3+0)*17+g]=cv0; xd[(c*3+1)*17+g]=cv1; xd[(c*3+2)*17+g]=cv2;
  }

  // ---- stage 4: crossfc (two 128-col halves) ----
  STAGE_W(gWfcAt, 16384);
  float fo[4][3];
#pragma unroll
  for (int k = 0; k < 4; ++k) { float bb = gbfcn[l+32*k]; fo[k][0]=bb; fo[k][1]=bb; fo[k][2]=bb; }
  MATVEC_ACC(xd, fo);

  STAGE_W(gWfcBt, 16384);
  MATVEC_ACC(xo, fo);

  // write out through xv (coalesced)
#pragma unroll
  for (int k = 0; k < 4; ++k) {
    int c = l + 32*k;
    xv[(c*3+0)*17+g]=fo[k][0]; xv[(c*3+1)*17+g]=fo[k][1]; xv[(c*3+2)*17+g]=fo[k][2];
  }
  __syncthreads();
  for (int i = tid; i < 6144; i += 512)
    out_v[vbase + (size_t)(i>>4)*4096 + (i&15)] = xv[(i>>4)*17 + (i&15)];
}

// ---------------- s-branch ----------------
__global__ __launch_bounds__(512, 1) void ks_kernel(
    const float* __restrict__ v_in, const float* __restrict__ s_in,
    const float* __restrict__ vs_b, const float* __restrict__ ss_b,
    const float* __restrict__ ws, float* __restrict__ out_s)
{
  const int b  = blockIdx.y;
  const int n0 = blockIdx.x * TS;
  const int tid = threadIdx.x;
  const int l = tid & 31;
  const int g = tid >> 5;

  const float* gVdirt = ws + OFF_VDIRT;
  const float* gVSt   = ws + OFF_VST;
  const float* gSSt   = ws + OFF_SST;
  const float* gbdirn = ws + OFF_BDIRN;

  __shared__ float Wt[16384];
  __shared__ float xv[384*17];
  __shared__ float st[64*TS];
  __shared__ float sfv[128*17];
  __shared__ float sou[64*17];

  const size_t vbase = ((size_t)b*384)*4096 + n0;
  for (int i = tid; i < 6144; i += 512)
    xv[(i>>4)*17 + (i&15)] = v_in[vbase + (size_t)(i>>4)*4096 + (i&15)];
  const size_t sbase = ((size_t)b*64)*4096 + n0;
  for (int i = tid; i < 1024; i += 512)
    st[i] = s_in[sbase + (size_t)(i>>4)*4096 + (i&15)];
  __syncthreads();

  // center v over channels (v_sR), keep own channels in regs
  float vloc[4][3];
  float vm0 = 0.f, vm1 = 0.f, vm2 = 0.f;
#pragma unroll
  for (int k = 0; k < 4; ++k) {
    int c = l + 32*k;
    vloc[k][0] = xv[(c*3+0)*17+g];
    vloc[k][1] = xv[(c*3+1)*17+g];
    vloc[k][2] = xv[(c*3+2)*17+g];
    vm0 += vloc[k][0]; vm1 += vloc[k][1]; vm2 += vloc[k][2];
  }
  vm0 = grp_sum(vm0)*(1.f/128.f);
  vm1 = grp_sum(vm1)*(1.f/128.f);
  vm2 = grp_sum(vm2)*(1.f/128.f);
#pragma unroll
  for (int k = 0; k < 4; ++k) {
    int c = l + 32*k;
    vloc[k][0]-=vm0; vloc[k][1]-=vm1; vloc[k][2]-=vm2;
    xv[(c*3+0)*17+g]=vloc[k][0]; xv[(c*3+1)*17+g]=vloc[k][1]; xv[(c*3+2)*17+g]=vloc[k][2];
  }

  // t = vsdir_w @ v_sR + eps_bias
  STAGE_W(gVdirt, 16384);
  float tt[4][3];
#pragma unroll
  for (int k = 0; k < 4; ++k) { float bb = gbdirn[l+32*k]; tt[k][0]=bb; tt[k][1]=bb; tt[k][2]=bb; }
  MATVEC_ACC(xv, tt);

  // s_from_v = l2n( (v_sR * l2n(t,axis=2)).sum(axis=2), channels )
  float sv[4];
  float n2loc = 0.f;
#pragma unroll
  for (int k = 0; k < 4; ++k) {
    float rnk = sqrtf(tt[k][0]*tt[k][0]+tt[k][1]*tt[k][1]+tt[k][2]*tt[k][2]);
    float inv = 1.f / fmaxf(rnk, 1e-12f);
    sv[k] = (vloc[k][0]*tt[k][0]+vloc[k][1]*tt[k][1]+vloc[k][2]*tt[k][2]) * inv;
    n2loc += sv[k]*sv[k];
  }
  float inv2 = 1.f / fmaxf(sqrtf(grp_sum(n2loc)), 1e-12f);
#pragma unroll
  for (int k = 0; k < 4; ++k) sfv[(l+32*k)*17+g] = sv[k]*inv2;

  // vs_w @ s_from_v + ss_w @ s + biases
  __syncthreads();
  for (int i = tid; i < 8192; i += 512) Wt[i] = gVSt[i];
  for (int i = tid; i < 4096; i += 512) Wt[8192+i] = gSSt[i];
  __syncthreads();

  float acc[2];
#pragma unroll
  for (int j = 0; j < 2; ++j) acc[j] = vs_b[l+32*j] + ss_b[l+32*j];
#pragma unroll 4
  for (int c = 0; c < 128; ++c) {
    float x = sfv[c*17+g];
#pragma unroll
    for (int j = 0; j < 2; ++j) acc[j] = fmaf(Wt[c*64 + l + 32*j], x, acc[j]);
  }
#pragma unroll 4
  for (int s = 0; s < 64; ++s) {
    float x = st[s*TS+g];
#pragma unroll
    for (int j = 0; j < 2; ++j) acc[j] = fmaf(Wt[8192 + s*64 + l + 32*j], x, acc[j]);
  }
#pragma unroll
  for (int j = 0; j < 2; ++j) sou[(l+32*j)*17+g] = acc[j];
  __syncthreads();
  const size_t obase = ((size_t)b*64)*4096 + n0;
  for (int i = tid; i < 1024; i += 512)
    out_s[obase + (size_t)(i>>4)*4096 + (i&15)] = sou[(i>>4)*17 + (i&15)];
}

extern "C" void kernel_launch(void* const* d_in, const int* in_sizes, int n_in,
                              void* d_out, int out_size, void* d_ws, size_t ws_size,
                              hipStream_t stream) {
  (void)in_sizes; (void)n_in; (void)out_size; (void)ws_size;
  const float* v_in      = (const float*)d_in[0];
  const float* s_in      = (const float*)d_in[1];
  const float* weight    = (const float*)d_in[2];
  const float* sv_w      = (const float*)d_in[3];
  const float* sv_b      = (const float*)d_in[4];
  const float* cross_w   = (const float*)d_in[5];
  const float* cross_b   = (const float*)d_in[6];
  const float* crossfc_w = (const float*)d_in[7];
  const float* crossfc_b = (const float*)d_in[8];
  const float* vsdir_w   = (const float*)d_in[9];
  const float* vsdir_b   = (const float*)d_in[10];
  const float* vs_w      = (const float*)d_in[11];
  const float* vs_b      = (const float*)d_in[12];
  const float* ss_w      = (const float*)d_in[13];
  const float* ss_b      = (const float*)d_in[14];
  float* out = (float*)d_out;
  float* ws  = (float*)d_ws;

  kprep<<<1, 128, 0, stream>>>(weight, cross_w, cross_b, crossfc_w, crossfc_b,
                               vsdir_w, vsdir_b, sv_w, vs_w, ss_w, ws);
  dim3 grid(4096/TS, 8);
  kv_kernel<<<grid, 512, 0, stream>>>(v_in, s_in, sv_b, ws, out);
  ks_kernel<<<grid, 512, 0, stream>>>(v_in, s_in, vs_b, ss_b, ws, out + VOUT_ELEMS);
}

// Round 2
// 96.256 us; speedup vs baseline: 6.3073x; 6.3073x over previous
//
#include <hip/hip_runtime.h>

#define TSB 32
#define VOUT_ELEMS 12582912   // 8*128*3*4096

typedef __attribute__((ext_vector_type(8))) short bf16x8;
typedef __attribute__((ext_vector_type(4))) float f32x4;

__device__ __forceinline__ unsigned short f2b(float f) {
  unsigned x = __float_as_uint(f);
  x = (x + 0x7FFFu + ((x >> 16) & 1u)) >> 16;
  return (unsigned short)x;
}
__device__ __forceinline__ float b2f(unsigned short u) {
  return __uint_as_float(((unsigned)u) << 16);
}
__device__ __forceinline__ unsigned pk2(float a, float b) {
  return (unsigned)f2b(a) | ((unsigned)f2b(b) << 16);
}

// ws layout (bf16 elems): aW1@0, aW2@16384, aFC@32768, aVD@65536, aSV@81920,
// aVS@90112, aSS@98304. f32 biases at byte 204800: b2n[128], bfcn[128], bdirn[128].

__global__ void kprep(const float* __restrict__ weight, const float* __restrict__ sv_w,
                      const float* __restrict__ cross_w, const float* __restrict__ cross_b,
                      const float* __restrict__ crossfc_w, const float* __restrict__ crossfc_b,
                      const float* __restrict__ vsdir_w, const float* __restrict__ vsdir_b,
                      const float* __restrict__ vs_w, const float* __restrict__ ss_w,
                      unsigned short* __restrict__ wsb, float* __restrict__ wsf)
{
  const int tid = threadIdx.x;           // 512
  const int bid = blockIdx.x;            // 8 blocks
  __shared__ float rs1[128], rs2[128], rsF[128], vdm[128], nrm[3];

  { // parallel row sums: 4 threads per output row
    int o = tid >> 2, part = tid & 3;
    float a = 0.f, b = 0.f, f = 0.f, v = 0.f;
    for (int c = part; c < 127; c += 4) { a += weight[o*127+c]; b += cross_w[o*127+c]; }
    for (int c = part; c < 255; c += 4) f += crossfc_w[o*255+c];
    for (int c = part; c < 128; c += 4) v += vsdir_w[o*128+c];
    a += __shfl_xor(a,1,64); a += __shfl_xor(a,2,64);
    b += __shfl_xor(b,1,64); b += __shfl_xor(b,2,64);
    f += __shfl_xor(f,1,64); f += __shfl_xor(f,2,64);
    v += __shfl_xor(v,1,64); v += __shfl_xor(v,2,64);
    if (part == 0) { rs1[o]=a; rs2[o]=b; rsF[o]=f; vdm[o]=v*(1.f/128.f); }
  }
  if (bid == 0) {
    const float* bsrc = (tid < 64) ? cross_b : (tid < 128 ? crossfc_b : vsdir_b);
    if (tid < 192) {
      int lane = tid & 63;
      float a = 0.f;
      for (int i = lane; i < 128; i += 64) { float t = bsrc[i]; a += t*t; }
      for (int m = 1; m < 64; m <<= 1) a += __shfl_xor(a, m, 64);
      if (lane == 0) nrm[tid >> 6] = sqrtf(a);
    }
  }
  __syncthreads();
  if (bid == 0 && tid < 128) {
    wsf[tid]     = cross_b[tid]   / fmaxf(nrm[0],1e-12f) * 1e-6f;
    wsf[128+tid] = crossfc_b[tid] / fmaxf(nrm[1],1e-12f) * 1e-6f;
    wsf[256+tid] = vsdir_b[tid]   / fmaxf(nrm[2],1e-12f) * 1e-6f;
  }
  const int stride = 512*8;
  const int base = bid*512 + tid;
  for (int i = base; i < 16384; i += stride) {
    int j=i&7, lane=(i>>3)&63, ks=(i>>9)&3, mt=i>>11;
    int o=16*mt+(lane&15), cc=32*ks+8*(lane>>4)+j;
    wsb[i]       = f2b(cc<127 ? weight[o*127+cc]  : 1.f-rs1[o]);
    wsb[16384+i] = f2b(cc<127 ? cross_w[o*127+cc] : 1.f-rs2[o]);
    wsb[65536+i] = f2b(vsdir_w[o*128+cc] - vdm[o]);
  }
  for (int i = base; i < 32768; i += stride) {
    int j=i&7, lane=(i>>3)&63, ks=(i>>9)&7, mt=i>>12;
    int o=16*mt+(lane&15), cc=32*ks+8*(lane>>4)+j;
    wsb[32768+i] = f2b(cc<255 ? crossfc_w[o*255+cc] : 1.f-rsF[o]);
  }
  for (int i = base; i < 8192; i += stride) {
    int j=i&7, lane=(i>>3)&63, ks=(i>>9)&1, mt=i>>10;
    int o=16*mt+(lane&15), s=32*ks+8*(lane>>4)+j;
    wsb[81920+i] = f2b(sv_w[o*64+s]);
  }
  for (int i = base; i < 8192; i += stride) {
    int j=i&7, lane=(i>>3)&63, ks=(i>>9)&3, mt=i>>11;   // mt 0..3
    int o=16*mt+(lane&15), c=32*ks+8*(lane>>4)+j;
    wsb[90112+i] = f2b(vs_w[o*128+c]);
  }
  for (int i = base; i < 4096; i += stride) {
    int j=i&7, lane=(i>>3)&63, ks=(i>>9)&1, mt=i>>10;
    int o=16*mt+(lane&15), s=32*ks+8*(lane>>4)+j;
    wsb[98304+i] = f2b(ss_w[o*64+s]);
  }
}

__global__ __launch_bounds__(512) void kmain(
    const float* __restrict__ v_in, const float* __restrict__ s_in,
    const float* __restrict__ sv_b, const float* __restrict__ vs_b,
    const float* __restrict__ ss_b,
    const unsigned short* __restrict__ wsb, const float* __restrict__ wsf,
    float* __restrict__ out_v, float* __restrict__ out_s)
{
  __shared__ unsigned short bfr[24576];  // B-frags: slot(ks 0..7, nt 0..5, lane, j)
  __shared__ unsigned short sfr[2048];   // s-input frags (ks 0..1, snt 0..1)
  __shared__ unsigned short vfr[4096];   // s_from_v frags (ks 0..3, snt 0..1)
  __shared__ float gmx[96];
  __shared__ float gmvo[96][8];
  __shared__ float gmdu[96][8];
  __shared__ float gd2[32][8];
  __shared__ float gsn[32][8];
  __shared__ float gmoo[96][8];
  __shared__ float gfn[32][8];

  const int tid = threadIdx.x;
  const int w = tid >> 6, l = tid & 63, h = l >> 4, c15 = l & 15;
  const int n0 = blockIdx.x * TSB;
  const size_t bb = blockIdx.y;
  const size_t vbase = bb*384*4096 + n0;
  const size_t sbase = bb*64*4096 + n0;

  // ---- phase A: scatter x and s tiles into bf16 B-fragments ----
  for (int it = 0; it < 6; ++it) {
    int idx = it*512 + tid;
    int row = idx >> 3, q = idx & 7;
    int c = row/3, d = row - 3*c;
    float4 x4 = *(const float4*)&v_in[vbase + (size_t)row*4096 + 4*q];
    int ks = c>>5, hh=(c>>3)&3, j=c&7;
    float vv[4] = {x4.x, x4.y, x4.z, x4.w};
#pragma unroll
    for (int e=0;e<4;++e) {
      int s = 4*q+e;
      bfr[(((ks*6 + 2*d + (s>>4)))*64 + 16*hh + (s&15))*8 + j] = f2b(vv[e]);
    }
  }
  {
    int sc = tid>>3, q = tid&7;
    float4 s4 = *(const float4*)&s_in[sbase + (size_t)sc*4096 + 4*q];
    int ks = sc>>5, hh=(sc>>3)&3, j=sc&7;
    float vv[4]={s4.x,s4.y,s4.z,s4.w};
#pragma unroll
    for (int e=0;e<4;++e){ int s=4*q+e;
      sfr[(((ks<<1)+(s>>4))*64 + 16*hh + (s&15))*8 + j] = f2b(vv[e]); }
  }
  __syncthreads();  // B1

  const bf16x8* bv  = (const bf16x8*)bfr;
  const bf16x8* sfv_p = (const bf16x8*)sfr;
  const bf16x8* vfv_p = (const bf16x8*)vfr;
  const bf16x8* wv  = (const bf16x8*)wsb;
  const int obase = 16*w + 4*h;

  // ---- phase B: W1, W2, Vdir', sv GEMMs + x-mean GEMV (all read-only LDS) ----
  f32x4 avo[6], adu[6], adr[6], asc[2];
#pragma unroll
  for (int nt=0;nt<6;++nt) {
    avo[nt] = (f32x4){0.f,0.f,0.f,0.f};
    adu[nt] = (f32x4){wsf[obase],wsf[obase+1],wsf[obase+2],wsf[obase+3]};
    adr[nt] = (f32x4){wsf[256+obase],wsf[256+obase+1],wsf[256+obase+2],wsf[256+obase+3]};
  }
  asc[0] = (f32x4){sv_b[obase],sv_b[obase+1],sv_b[obase+2],sv_b[obase+3]};
  asc[1] = asc[0];

#pragma unroll
  for (int ks=0;ks<4;++ks) {
    bf16x8 a1 = wv[(w*4+ks)*64 + l];
    bf16x8 a2 = wv[2048 + (w*4+ks)*64 + l];
    bf16x8 a3 = wv[8192 + (w*4+ks)*64 + l];
#pragma unroll
    for (int nt=0;nt<6;++nt) {
      bf16x8 bx = bv[(ks*6+nt)*64 + l];
      avo[nt] = __builtin_amdgcn_mfma_f32_16x16x32_bf16(a1, bx, avo[nt], 0,0,0);
      adu[nt] = __builtin_amdgcn_mfma_f32_16x16x32_bf16(a2, bx, adu[nt], 0,0,0);
      adr[nt] = __builtin_amdgcn_mfma_f32_16x16x32_bf16(a3, bx, adr[nt], 0,0,0);
    }
  }
#pragma unroll
  for (int ks=0;ks<2;++ks) {
    bf16x8 a4 = wv[10240 + (w*2+ks)*64 + l];
#pragma unroll
    for (int snt=0;snt<2;++snt)
      asc[snt] = __builtin_amdgcn_mfma_f32_16x16x32_bf16(a4, sfv_p[(ks*2+snt)*64+l], asc[snt], 0,0,0);
  }
  if (w < 6) {  // x channel-mean via ones-row GEMV, wave w handles nt = w
    bf16x8 aone;
#pragma unroll
    for (int j=0;j<8;++j) aone[j] = (short)0x3C00;  // bf16(1/128)
    f32x4 amx = (f32x4){0.f,0.f,0.f,0.f};
#pragma unroll
    for (int ks=0;ks<4;++ks)
      amx = __builtin_amdgcn_mfma_f32_16x16x32_bf16(aone, bv[(ks*6+w)*64+l], amx, 0,0,0);
    if (h==0) gmx[16*w + c15] = amx[0];
  }

  // cross-wave partials round 1
  float pv[6], pd[6], pd2[2] = {0.f,0.f};
#pragma unroll
  for (int nt=0;nt<6;++nt) {
    pv[nt] = avo[nt][0]+avo[nt][1]+avo[nt][2]+avo[nt][3];
    pd[nt] = adu[nt][0]+adu[nt][1]+adu[nt][2]+adu[nt][3];
    pd2[nt&1] += adu[nt][0]*adu[nt][0]+adu[nt][1]*adu[nt][1]
               + adu[nt][2]*adu[nt][2]+adu[nt][3]*adu[nt][3];
  }
  float ps0 = asc[0][0]*asc[0][0]+asc[0][1]*asc[0][1]+asc[0][2]*asc[0][2]+asc[0][3]*asc[0][3];
  float ps1 = asc[1][0]*asc[1][0]+asc[1][1]*asc[1][1]+asc[1][2]*asc[1][2]+asc[1][3]*asc[1][3];
#pragma unroll
  for (int m=16;m<64;m<<=1) {
#pragma unroll
    for (int nt=0;nt<6;++nt) { pv[nt]+=__shfl_xor(pv[nt],m,64); pd[nt]+=__shfl_xor(pd[nt],m,64); }
    pd2[0]+=__shfl_xor(pd2[0],m,64); pd2[1]+=__shfl_xor(pd2[1],m,64);
    ps0+=__shfl_xor(ps0,m,64); ps1+=__shfl_xor(ps1,m,64);
  }
  if (h==0) {
#pragma unroll
    for (int nt=0;nt<6;++nt) { gmvo[16*nt+c15][w]=pv[nt]; gmdu[16*nt+c15][w]=pd[nt]; }
    gd2[c15][w]=pd2[0]; gd2[16+c15][w]=pd2[1];
    gsn[c15][w]=ps0;    gsn[16+c15][w]=ps1;
  }
  __syncthreads(); // B2

  float mvo[6], mdu[6], mxv[6];
#pragma unroll
  for (int nt=0;nt<6;++nt) {
    int col = 16*nt + c15;
    const f32x4* p  = (const f32x4*)gmvo[col];
    const f32x4* p2 = (const f32x4*)gmdu[col];
    f32x4 x0=p[0], x1=p[1], y0=p2[0], y1=p2[1];
    mvo[nt] = (x0[0]+x0[1]+x0[2]+x0[3]+x1[0]+x1[1]+x1[2]+x1[3]) * (1.f/128.f);
    mdu[nt] = (y0[0]+y0[1]+y0[2]+y0[3]+y1[0]+y1[1]+y1[2]+y1[3]) * (1.f/128.f);
    mxv[nt] = gmx[col];
  }
  float sinv2[2], d2s[2];
#pragma unroll
  for (int sh=0; sh<2; ++sh) {
    int site = 16*sh + c15;
    const f32x4* pa = (const f32x4*)gsn[site];
    const f32x4* pb = (const f32x4*)gd2[site];
    f32x4 a0=pa[0],a1=pa[1],b0=pb[0],b1=pb[1];
    float n2 = a0[0]+a0[1]+a0[2]+a0[3]+a1[0]+a1[1]+a1[2]+a1[3];
    sinv2[sh] = 1.f / fmaxf(sqrtf(n2), 1e-12f);
    d2s[sh] = b0[0]+b0[1]+b0[2]+b0[3]+b1[0]+b1[1]+b1[2]+b1[3];
  }
  // apply invariant scale to v_o; accumulate out_o partials
  float po[6];
#pragma unroll
  for (int nt=0;nt<6;++nt) {
    int sh = nt&1;
#pragma unroll
    for (int r=0;r<4;++r) {
      float sk = asc[sh][r] * sinv2[sh];
      avo[nt][r] = (avo[nt][r] - mvo[nt])*sk + mvo[nt];
    }
    po[nt] = avo[nt][0]+avo[nt][1]+avo[nt][2]+avo[nt][3];
  }
  // v_sR readback (x still intact), dir normalize, invariant dot
  const int ksx = w>>1;
  const int laneP = 16*(2*(w&1) + (h>>1)) + c15;
  const int j0 = 4*(h&1);
  float xr[6][4];
#pragma unroll
  for (int nt=0;nt<6;++nt) {
    const unsigned* px = (const unsigned*)&bfr[(((ksx*6+nt))*64+laneP)*8 + j0];
    unsigned u0 = px[0], u1 = px[1];
    xr[nt][0]=b2f((unsigned short)u0);  xr[nt][1]=b2f((unsigned short)(u0>>16));
    xr[nt][2]=b2f((unsigned short)u1);  xr[nt][3]=b2f((unsigned short)(u1>>16));
  }
  float sfv[2][4]; float pfn[2]={0.f,0.f};
#pragma unroll
  for (int sh=0;sh<2;++sh) {
#pragma unroll
    for (int r=0;r<4;++r) {
      float dx=adr[sh][r], dy=adr[2+sh][r], dz=adr[4+sh][r];
      float rn = sqrtf(dx*dx+dy*dy+dz*dz);
      float inv = 1.f/fmaxf(rn,1e-12f);
      float vx = xr[sh][r]-mxv[sh], vy = xr[2+sh][r]-mxv[2+sh], vz = xr[4+sh][r]-mxv[4+sh];
      float dot = (vx*dx+vy*dy+vz*dz)*inv;
      sfv[sh][r]=dot; pfn[sh]+=dot*dot;
    }
  }
#pragma unroll
  for (int m=16;m<64;m<<=1) {
    pfn[0]+=__shfl_xor(pfn[0],m,64); pfn[1]+=__shfl_xor(pfn[1],m,64);
#pragma unroll
    for (int nt=0;nt<6;++nt) po[nt]+=__shfl_xor(po[nt],m,64);
  }
  if (h==0) {
#pragma unroll
    for (int nt=0;nt<6;++nt) gmoo[16*nt+c15][w]=po[nt];
    gfn[c15][w]=pfn[0]; gfn[16+c15][w]=pfn[1];
  }
  __syncthreads(); // B2b (also fences x reads before xd overwrites)

  float moo[6];
#pragma unroll
  for (int nt=0;nt<6;++nt) {
    const f32x4* p = (const f32x4*)gmoo[16*nt+c15];
    f32x4 x0=p[0], x1=p[1];
    moo[nt] = (x0[0]+x0[1]+x0[2]+x0[3]+x1[0]+x1[1]+x1[2]+x1[3]) * (1.f/128.f);
  }
  float sfni[2];
#pragma unroll
  for (int sh=0;sh<2;++sh) {
    const f32x4* p = (const f32x4*)gfn[16*sh+c15];
    f32x4 x0=p[0], x1=p[1];
    sfni[sh] = 1.f/fmaxf(sqrtf(x0[0]+x0[1]+x0[2]+x0[3]+x1[0]+x1[1]+x1[2]+x1[3]),1e-12f);
  }
  // write s_from_v fragments; compute cross, write xd (v_cross) + xo (v_o) fragments
#pragma unroll
  for (int sh=0;sh<2;++sh) {
    unsigned* dv = (unsigned*)&vfr[(((ksx*2+sh))*64+laneP)*8 + j0];
    dv[0] = pk2(sfv[sh][0]*sfni[sh], sfv[sh][1]*sfni[sh]);
    dv[1] = pk2(sfv[sh][2]*sfni[sh], sfv[sh][3]*sfni[sh]);

    float m2 = mdu[sh]*mdu[sh]+mdu[2+sh]*mdu[2+sh]+mdu[4+sh]*mdu[4+sh];
    float F  = sqrtf(fmaxf(d2s[sh]-128.f*m2, 0.f));
    float Fi = 1.f/fmaxf(F,1e-12f);
    float cx[4],cy[4],cz[4];
#pragma unroll
    for (int r=0;r<4;++r) {
      float ax=adu[sh][r]-mdu[sh], ay=adu[2+sh][r]-mdu[2+sh], az=adu[4+sh][r]-mdu[4+sh];
      float rn = sqrtf(ax*ax+ay*ay+az*az);
      float s1 = (rn*Fi)/fmaxf(rn,1e-12f);
      ax*=s1; ay*=s1; az*=s1;
      float bx=avo[sh][r]-moo[sh], by=avo[2+sh][r]-moo[2+sh], bz=avo[4+sh][r]-moo[4+sh];
      cx[r]=ay*bz-az*by+avo[sh][r];
      cy[r]=az*bx-ax*bz+avo[2+sh][r];
      cz[r]=ax*by-ay*bx+avo[4+sh][r];
    }
    unsigned* d0 = (unsigned*)&bfr[((ksx*6+sh)*64+laneP)*8 + j0];
    d0[0]=pk2(cx[0],cx[1]); d0[1]=pk2(cx[2],cx[3]);
    unsigned* d1 = (unsigned*)&bfr[((ksx*6+2+sh)*64+laneP)*8 + j0];
    d1[0]=pk2(cy[0],cy[1]); d1[1]=pk2(cy[2],cy[3]);
    unsigned* d2p = (unsigned*)&bfr[((ksx*6+4+sh)*64+laneP)*8 + j0];
    d2p[0]=pk2(cz[0],cz[1]); d2p[1]=pk2(cz[2],cz[3]);
    unsigned* e0 = (unsigned*)&bfr[(((4+ksx)*6+sh)*64+laneP)*8 + j0];
    e0[0]=pk2(avo[sh][0],avo[sh][1]); e0[1]=pk2(avo[sh][2],avo[sh][3]);
    unsigned* e1 = (unsigned*)&bfr[(((4+ksx)*6+2+sh)*64+laneP)*8 + j0];
    e1[0]=pk2(avo[2+sh][0],avo[2+sh][1]); e1[1]=pk2(avo[2+sh][2],avo[2+sh][3]);
    unsigned* e2 = (unsigned*)&bfr[(((4+ksx)*6+4+sh)*64+laneP)*8 + j0];
    e2[0]=pk2(avo[4+sh][0],avo[4+sh][1]); e2[1]=pk2(avo[4+sh][2],avo[4+sh][3]);
  }
  __syncthreads(); // B3

  // ---- phase C: crossfc (K=256) + s-path GEMMs ----
  f32x4 afc[6];
#pragma unroll
  for (int nt=0;nt<6;++nt)
    afc[nt]=(f32x4){wsf[128+obase],wsf[128+obase+1],wsf[128+obase+2],wsf[128+obase+3]};
#pragma unroll
  for (int ks=0;ks<8;++ks) {
    bf16x8 a5 = wv[4096 + (w*8+ks)*64 + l];
#pragma unroll
    for (int nt=0;nt<6;++nt)
      afc[nt] = __builtin_amdgcn_mfma_f32_16x16x32_bf16(a5, bv[(ks*6+nt)*64+l], afc[nt], 0,0,0);
  }
#pragma unroll
  for (int nt=0;nt<6;++nt) {
    int d = nt>>1, site = 16*(nt&1)+c15;
#pragma unroll
    for (int r=0;r<4;++r)
      out_v[vbase + (size_t)((obase+r)*3 + d)*4096 + site] = afc[nt][r];
  }
  if (w < 4) {
    f32x4 as2[2];
    as2[0] = (f32x4){vs_b[obase]+ss_b[obase],   vs_b[obase+1]+ss_b[obase+1],
                     vs_b[obase+2]+ss_b[obase+2], vs_b[obase+3]+ss_b[obase+3]};
    as2[1] = as2[0];
#pragma unroll
    for (int ks=0;ks<4;++ks) {
      bf16x8 a6 = wv[11264 + (w*4+ks)*64 + l];
#pragma unroll
      for (int snt=0;snt<2;++snt)
        as2[snt] = __builtin_amdgcn_mfma_f32_16x16x32_bf16(a6, vfv_p[(ks*2+snt)*64+l], as2[snt], 0,0,0);
    }
#pragma unroll
    for (int ks=0;ks<2;++ks) {
      bf16x8 a7 = wv[12288 + (w*2+ks)*64 + l];
#pragma unroll
      for (int snt=0;snt<2;++snt)
        as2[snt] = __builtin_amdgcn_mfma_f32_16x16x32_bf16(a7, sfv_p[(ks*2+snt)*64+l], as2[snt], 0,0,0);
    }
#pragma unroll
    for (int snt=0;snt<2;++snt)
#pragma unroll
      for (int r=0;r<4;++r)
        out_s[sbase + (size_t)(obase+r)*4096 + 16*snt + c15] = as2[snt][r];
  }
}

extern "C" void kernel_launch(void* const* d_in, const int* in_sizes, int n_in,
                              void* d_out, int out_size, void* d_ws, size_t ws_size,
                              hipStream_t stream) {
  (void)in_sizes; (void)n_in; (void)out_size; (void)ws_size;
  const float* v_in      = (const float*)d_in[0];
  const float* s_in      = (const float*)d_in[1];
  const float* weight    = (const float*)d_in[2];
  const float* sv_w      = (const float*)d_in[3];
  const float* sv_b      = (const float*)d_in[4];
  const float* cross_w   = (const float*)d_in[5];
  const float* cross_b   = (const float*)d_in[6];
  const float* crossfc_w = (const float*)d_in[7];
  const float* crossfc_b = (const float*)d_in[8];
  const float* vsdir_w   = (const float*)d_in[9];
  const float* vsdir_b   = (const float*)d_in[10];
  const float* vs_w      = (const float*)d_in[11];
  const float* vs_b      = (const float*)d_in[12];
  const float* ss_w      = (const float*)d_in[13];
  const float* ss_b      = (const float*)d_in[14];

  unsigned short* wsb = (unsigned short*)d_ws;
  float* wsf = (float*)((char*)d_ws + 204800);

  kprep<<<8, 512, 0, stream>>>(weight, sv_w, cross_w, cross_b, crossfc_w, crossfc_b,
                               vsdir_w, vsdir_b, vs_w, ss_w, wsb, wsf);
  dim3 grid(4096/TSB, 8);
  kmain<<<grid, 512, 0, stream>>>(v_in, s_in, sv_b, vs_b, ss_b, wsb, wsf,
                                  (float*)d_out, (float*)d_out + VOUT_ELEMS);
}

// Round 4
// 94.657 us; speedup vs baseline: 6.4139x; 1.0169x over previous
//
#include <hip/hip_runtime.h>

#define TSB 32
#define VOUT_ELEMS 12582912   // 8*128*3*4096

typedef __attribute__((ext_vector_type(8))) short bf16x8;
typedef __attribute__((ext_vector_type(4))) float f32x4;

__device__ __forceinline__ unsigned short f2b(float f) {
  unsigned x = __float_as_uint(f);
  x = (x + 0x7FFFu + ((x >> 16) & 1u)) >> 16;
  return (unsigned short)x;
}
__device__ __forceinline__ float b2f(unsigned short u) {
  return __uint_as_float(((unsigned)u) << 16);
}
__device__ __forceinline__ unsigned pk2(float a, float b) {
  unsigned r;
  asm("v_cvt_pk_bf16_f32 %0, %1, %2" : "=v"(r) : "v"(a), "v"(b));
  return r;
}

// ws layout (bf16 elems): aW1@0, aW2@16384, aFC@32768, aVD@65536, aSV@81920,
// aVS@90112, aSS@98304. f32 biases at byte 204800: b2n[128], bfcn[128], bdirn[128].

__global__ void kprep(const float* __restrict__ weight, const float* __restrict__ sv_w,
                      const float* __restrict__ cross_w, const float* __restrict__ cross_b,
                      const float* __restrict__ crossfc_w, const float* __restrict__ crossfc_b,
                      const float* __restrict__ vsdir_w, const float* __restrict__ vsdir_b,
                      const float* __restrict__ vs_w, const float* __restrict__ ss_w,
                      unsigned short* __restrict__ wsb, float* __restrict__ wsf)
{
  const int tid = threadIdx.x;           // 512
  const int bid = blockIdx.x;            // 8 blocks
  __shared__ float rs1[128], rs2[128], rsF[128], vdm[128], nrm[3];

  { // parallel row sums: 4 threads per output row
    int o = tid >> 2, part = tid & 3;
    float a = 0.f, b = 0.f, f = 0.f, v = 0.f;
    for (int c = part; c < 127; c += 4) { a += weight[o*127+c]; b += cross_w[o*127+c]; }
    for (int c = part; c < 255; c += 4) f += crossfc_w[o*255+c];
    for (int c = part; c < 128; c += 4) v += vsdir_w[o*128+c];
    a += __shfl_xor(a,1,64); a += __shfl_xor(a,2,64);
    b += __shfl_xor(b,1,64); b += __shfl_xor(b,2,64);
    f += __shfl_xor(f,1,64); f += __shfl_xor(f,2,64);
    v += __shfl_xor(v,1,64); v += __shfl_xor(v,2,64);
    if (part == 0) { rs1[o]=a; rs2[o]=b; rsF[o]=f; vdm[o]=v*(1.f/128.f); }
  }
  if (bid == 0) {
    const float* bsrc = (tid < 64) ? cross_b : (tid < 128 ? crossfc_b : vsdir_b);
    if (tid < 192) {
      int lane = tid & 63;
      float a = 0.f;
      for (int i = lane; i < 128; i += 64) { float t = bsrc[i]; a += t*t; }
      for (int m = 1; m < 64; m <<= 1) a += __shfl_xor(a, m, 64);
      if (lane == 0) nrm[tid >> 6] = sqrtf(a);
    }
  }
  __syncthreads();
  if (bid == 0 && tid < 128) {
    wsf[tid]     = cross_b[tid]   / fmaxf(nrm[0],1e-12f) * 1e-6f;
    wsf[128+tid] = crossfc_b[tid] / fmaxf(nrm[1],1e-12f) * 1e-6f;
    wsf[256+tid] = vsdir_b[tid]   / fmaxf(nrm[2],1e-12f) * 1e-6f;
  }
  const int stride = 512*8;
  const int base = bid*512 + tid;
  for (int i = base; i < 16384; i += stride) {
    int j=i&7, lane=(i>>3)&63, ks=(i>>9)&3, mt=i>>11;
    int o=16*mt+(lane&15), cc=32*ks+8*(lane>>4)+j;
    wsb[i]       = f2b(cc<127 ? weight[o*127+cc]  : 1.f-rs1[o]);
    wsb[16384+i] = f2b(cc<127 ? cross_w[o*127+cc] : 1.f-rs2[o]);
    wsb[65536+i] = f2b(vsdir_w[o*128+cc] - vdm[o]);
  }
  for (int i = base; i < 32768; i += stride) {
    int j=i&7, lane=(i>>3)&63, ks=(i>>9)&7, mt=i>>12;
    int o=16*mt+(lane&15), cc=32*ks+8*(lane>>4)+j;
    wsb[32768+i] = f2b(cc<255 ? crossfc_w[o*255+cc] : 1.f-rsF[o]);
  }
  for (int i = base; i < 8192; i += stride) {
    int j=i&7, lane=(i>>3)&63, ks=(i>>9)&1, mt=i>>10;
    int o=16*mt+(lane&15), s=32*ks+8*(lane>>4)+j;
    wsb[81920+i] = f2b(sv_w[o*64+s]);
  }
  for (int i = base; i < 8192; i += stride) {
    int j=i&7, lane=(i>>3)&63, ks=(i>>9)&3, mt=i>>11;   // mt 0..3
    int o=16*mt+(lane&15), c=32*ks+8*(lane>>4)+j;
    wsb[90112+i] = f2b(vs_w[o*128+c]);
  }
  for (int i = base; i < 4096; i += stride) {
    int j=i&7, lane=(i>>3)&63, ks=(i>>9)&1, mt=i>>10;
    int o=16*mt+(lane&15), s=32*ks+8*(lane>>4)+j;
    wsb[98304+i] = f2b(ss_w[o*64+s]);
  }
}

__global__ __launch_bounds__(512) void kmain(
    const float* __restrict__ v_in, const float* __restrict__ s_in,
    const float* __restrict__ sv_b, const float* __restrict__ vs_b,
    const float* __restrict__ ss_b,
    const unsigned short* __restrict__ wsb, const float* __restrict__ wsf,
    float* __restrict__ out_v, float* __restrict__ out_s)
{
  __shared__ unsigned short bfr[24576];  // B-frags: slot(ks 0..7, nt 0..5, lane, j)
  __shared__ unsigned short sfr[2048];   // s-input frags (ks 0..1, snt 0..1)
  __shared__ unsigned short vfr[4096];   // s_from_v frags (ks 0..3, snt 0..1)
  __shared__ float gmx[96];
  __shared__ float gmvo[96][8];
  __shared__ float gmdu[96][8];
  __shared__ float gd2[32][8];
  __shared__ float gsn[32][8];
  __shared__ float gmoo[96][8];
  __shared__ float gfn[32][8];

  const int tid = threadIdx.x;
  const int w = tid >> 6, l = tid & 63, h = l >> 4, c15 = l & 15;
  const int n0 = blockIdx.x * TSB;
  const size_t bb = blockIdx.y;
  const size_t vbase = bb*384*4096 + n0;
  const size_t sbase = bb*64*4096 + n0;

  // ---- phase A: quad-channel pair-packed scatter into bf16 B-fragments ----
  // v: 768 tasks (cq 0..31, d 0..2, q 0..7); each loads 4 rows x float4, stores 4 uint2
  for (int i = tid; i < 768; i += 512) {
    int q = i & 7, d = (i >> 3) % 3, cq = i / 24;
    const float* src = &v_in[vbase + (size_t)(4*cq*3 + d)*4096 + 4*q];
    float4 x0 = *(const float4*)(src);
    float4 x1 = *(const float4*)(src + 3*4096);
    float4 x2 = *(const float4*)(src + 6*4096);
    float4 x3 = *(const float4*)(src + 9*4096);
    int snt = q >> 2;
    int slot = (cq >> 3)*6 + 2*d + snt;
    int hh = (cq >> 1) & 3;
    int jp = 2*(cq & 1);
    int s15 = (4*q) & 15;
    unsigned* bp = (unsigned*)bfr + (slot*64 + 16*hh + s15)*4 + jp;
    float a0[4]={x0.x,x0.y,x0.z,x0.w}, a1[4]={x1.x,x1.y,x1.z,x1.w};
    float a2[4]={x2.x,x2.y,x2.z,x2.w}, a3[4]={x3.x,x3.y,x3.z,x3.w};
#pragma unroll
    for (int e=0;e<4;++e)
      *(uint2*)(bp + e*4) = make_uint2(pk2(a0[e],a1[e]), pk2(a2[e],a3[e]));
  }
  // s: 128 tasks (sq 0..15, q 0..7)
  if (tid < 128) {
    int q = tid & 7, sq = tid >> 3;
    const float* src = &s_in[sbase + (size_t)(4*sq)*4096 + 4*q];
    float4 x0 = *(const float4*)(src);
    float4 x1 = *(const float4*)(src + 4096);
    float4 x2 = *(const float4*)(src + 2*4096);
    float4 x3 = *(const float4*)(src + 3*4096);
    int snt = q >> 2;
    int slot = (sq >> 3)*2 + snt;
    int hh = (sq >> 1) & 3;
    int jp = 2*(sq & 1);
    int s15 = (4*q) & 15;
    unsigned* bp = (unsigned*)sfr + (slot*64 + 16*hh + s15)*4 + jp;
    float a0[4]={x0.x,x0.y,x0.z,x0.w}, a1[4]={x1.x,x1.y,x1.z,x1.w};
    float a2[4]={x2.x,x2.y,x2.z,x2.w}, a3[4]={x3.x,x3.y,x3.z,x3.w};
#pragma unroll
    for (int e=0;e<4;++e)
      *(uint2*)(bp + e*4) = make_uint2(pk2(a0[e],a1[e]), pk2(a2[e],a3[e]));
  }
  __syncthreads();  // B1

  const bf16x8* bv  = (const bf16x8*)bfr;
  const bf16x8* sfv_p = (const bf16x8*)sfr;
  const bf16x8* vfv_p = (const bf16x8*)vfr;
  const bf16x8* wv  = (const bf16x8*)wsb;
  const int obase = 16*w + 4*h;

  // ---- phase B: W1, W2, Vdir', sv GEMMs + x-mean GEMV ----
  f32x4 avo[6], adu[6], adr[6], asc[2];
#pragma unroll
  for (int nt=0;nt<6;++nt) {
    avo[nt] = (f32x4){0.f,0.f,0.f,0.f};
    adu[nt] = (f32x4){wsf[obase],wsf[obase+1],wsf[obase+2],wsf[obase+3]};
    adr[nt] = (f32x4){wsf[256+obase],wsf[256+obase+1],wsf[256+obase+2],wsf[256+obase+3]};
  }
  asc[0] = (f32x4){sv_b[obase],sv_b[obase+1],sv_b[obase+2],sv_b[obase+3]};
  asc[1] = asc[0];

#pragma unroll
  for (int ks=0;ks<4;++ks) {
    bf16x8 a1 = wv[(w*4+ks)*64 + l];
    bf16x8 a2 = wv[2048 + (w*4+ks)*64 + l];
    bf16x8 a3 = wv[8192 + (w*4+ks)*64 + l];
#pragma unroll
    for (int nt=0;nt<6;++nt) {
      bf16x8 bx = bv[(ks*6+nt)*64 + l];
      avo[nt] = __builtin_amdgcn_mfma_f32_16x16x32_bf16(a1, bx, avo[nt], 0,0,0);
      adu[nt] = __builtin_amdgcn_mfma_f32_16x16x32_bf16(a2, bx, adu[nt], 0,0,0);
      adr[nt] = __builtin_amdgcn_mfma_f32_16x16x32_bf16(a3, bx, adr[nt], 0,0,0);
    }
  }
#pragma unroll
  for (int ks=0;ks<2;++ks) {
    bf16x8 a4 = wv[10240 + (w*2+ks)*64 + l];
#pragma unroll
    for (int snt=0;snt<2;++snt)
      asc[snt] = __builtin_amdgcn_mfma_f32_16x16x32_bf16(a4, sfv_p[(ks*2+snt)*64+l], asc[snt], 0,0,0);
  }
  if (w < 6) {  // x channel-mean via ones-row GEMV, wave w handles nt = w
    bf16x8 aone;
#pragma unroll
    for (int j=0;j<8;++j) aone[j] = (short)0x3C00;  // bf16(1/128)
    f32x4 amx = (f32x4){0.f,0.f,0.f,0.f};
#pragma unroll
    for (int ks=0;ks<4;++ks)
      amx = __builtin_amdgcn_mfma_f32_16x16x32_bf16(aone, bv[(ks*6+w)*64+l], amx, 0,0,0);
    if (h==0) gmx[16*w + c15] = amx[0];
  }

  // cross-wave partials round 1
  float pv[6], pd[6], pd2[2] = {0.f,0.f};
#pragma unroll
  for (int nt=0;nt<6;++nt) {
    pv[nt] = avo[nt][0]+avo[nt][1]+avo[nt][2]+avo[nt][3];
    pd[nt] = adu[nt][0]+adu[nt][1]+adu[nt][2]+adu[nt][3];
    pd2[nt&1] += adu[nt][0]*adu[nt][0]+adu[nt][1]*adu[nt][1]
               + adu[nt][2]*adu[nt][2]+adu[nt][3]*adu[nt][3];
  }
  float ps0 = asc[0][0]*asc[0][0]+asc[0][1]*asc[0][1]+asc[0][2]*asc[0][2]+asc[0][3]*asc[0][3];
  float ps1 = asc[1][0]*asc[1][0]+asc[1][1]*asc[1][1]+asc[1][2]*asc[1][2]+asc[1][3]*asc[1][3];
#pragma unroll
  for (int m=16;m<64;m<<=1) {
#pragma unroll
    for (int nt=0;nt<6;++nt) { pv[nt]+=__shfl_xor(pv[nt],m,64); pd[nt]+=__shfl_xor(pd[nt],m,64); }
    pd2[0]+=__shfl_xor(pd2[0],m,64); pd2[1]+=__shfl_xor(pd2[1],m,64);
    ps0+=__shfl_xor(ps0,m,64); ps1+=__shfl_xor(ps1,m,64);
  }
  if (h==0) {
#pragma unroll
    for (int nt=0;nt<6;++nt) { gmvo[16*nt+c15][w]=pv[nt]; gmdu[16*nt+c15][w]=pd[nt]; }
    gd2[c15][w]=pd2[0]; gd2[16+c15][w]=pd2[1];
    gsn[c15][w]=ps0;    gsn[16+c15][w]=ps1;
  }
  __syncthreads(); // B2

  float mvo[6], mdu[6], mxv[6];
#pragma unroll
  for (int nt=0;nt<6;++nt) {
    int col = 16*nt + c15;
    const f32x4* p  = (const f32x4*)gmvo[col];
    const f32x4* p2 = (const f32x4*)gmdu[col];
    f32x4 x0=p[0], x1=p[1], y0=p2[0], y1=p2[1];
    mvo[nt] = (x0[0]+x0[1]+x0[2]+x0[3]+x1[0]+x1[1]+x1[2]+x1[3]) * (1.f/128.f);
    mdu[nt] = (y0[0]+y0[1]+y0[2]+y0[3]+y1[0]+y1[1]+y1[2]+y1[3]) * (1.f/128.f);
    mxv[nt] = gmx[col];
  }
  float sinv2[2], d2s[2];
#pragma unroll
  for (int sh=0; sh<2; ++sh) {
    int site = 16*sh + c15;
    const f32x4* pa = (const f32x4*)gsn[site];
    const f32x4* pb = (const f32x4*)gd2[site];
    f32x4 a0=pa[0],a1=pa[1],b0=pb[0],b1=pb[1];
    float n2 = a0[0]+a0[1]+a0[2]+a0[3]+a1[0]+a1[1]+a1[2]+a1[3];
    sinv2[sh] = 1.f / fmaxf(sqrtf(n2), 1e-12f);
    d2s[sh] = b0[0]+b0[1]+b0[2]+b0[3]+b1[0]+b1[1]+b1[2]+b1[3];
  }
  // apply invariant scale to v_o; accumulate out_o partials
  float po[6];
#pragma unroll
  for (int nt=0;nt<6;++nt) {
    int sh = nt&1;
#pragma unroll
    for (int r=0;r<4;++r) {
      float sk = asc[sh][r] * sinv2[sh];
      avo[nt][r] = (avo[nt][r] - mvo[nt])*sk + mvo[nt];
    }
    po[nt] = avo[nt][0]+avo[nt][1]+avo[nt][2]+avo[nt][3];
  }
  // v_sR readback (x still intact), dir normalize, invariant dot
  const int ksx = w>>1;
  const int laneP = 16*(2*(w&1) + (h>>1)) + c15;
  const int j0 = 4*(h&1);
  float xr[6][4];
#pragma unroll
  for (int nt=0;nt<6;++nt) {
    const unsigned* px = (const unsigned*)&bfr[(((ksx*6+nt))*64+laneP)*8 + j0];
    unsigned u0 = px[0], u1 = px[1];
    xr[nt][0]=b2f((unsigned short)u0);  xr[nt][1]=b2f((unsigned short)(u0>>16));
    xr[nt][2]=b2f((unsigned short)u1);  xr[nt][3]=b2f((unsigned short)(u1>>16));
  }
  float sfv[2][4]; float pfn[2]={0.f,0.f};
#pragma unroll
  for (int sh=0;sh<2;++sh) {
#pragma unroll
    for (int r=0;r<4;++r) {
      float dx=adr[sh][r], dy=adr[2+sh][r], dz=adr[4+sh][r];
      float rn = sqrtf(dx*dx+dy*dy+dz*dz);
      float inv = 1.f/fmaxf(rn,1e-12f);
      float vx = xr[sh][r]-mxv[sh], vy = xr[2+sh][r]-mxv[2+sh], vz = xr[4+sh][r]-mxv[4+sh];
      float dot = (vx*dx+vy*dy+vz*dz)*inv;
      sfv[sh][r]=dot; pfn[sh]+=dot*dot;
    }
  }
#pragma unroll
  for (int m=16;m<64;m<<=1) {
    pfn[0]+=__shfl_xor(pfn[0],m,64); pfn[1]+=__shfl_xor(pfn[1],m,64);
#pragma unroll
    for (int nt=0;nt<6;++nt) po[nt]+=__shfl_xor(po[nt],m,64);
  }
  if (h==0) {
#pragma unroll
    for (int nt=0;nt<6;++nt) gmoo[16*nt+c15][w]=po[nt];
    gfn[c15][w]=pfn[0]; gfn[16+c15][w]=pfn[1];
  }
  __syncthreads(); // B2b (also fences x reads before xd overwrites)

  float moo[6];
#pragma unroll
  for (int nt=0;nt<6;++nt) {
    const f32x4* p = (const f32x4*)gmoo[16*nt+c15];
    f32x4 x0=p[0], x1=p[1];
    moo[nt] = (x0[0]+x0[1]+x0[2]+x0[3]+x1[0]+x1[1]+x1[2]+x1[3]) * (1.f/128.f);
  }
  float sfni[2];
#pragma unroll
  for (int sh=0;sh<2;++sh) {
    const f32x4* p = (const f32x4*)gfn[16*sh+c15];
    f32x4 x0=p[0], x1=p[1];
    sfni[sh] = 1.f/fmaxf(sqrtf(x0[0]+x0[1]+x0[2]+x0[3]+x1[0]+x1[1]+x1[2]+x1[3]),1e-12f);
  }
  // write s_from_v fragments; compute cross, write xd (v_cross) + xo (v_o) fragments
#pragma unroll
  for (int sh=0;sh<2;++sh) {
    *(uint2*)&vfr[(((ksx*2+sh))*64+laneP)*8 + j0] =
      make_uint2(pk2(sfv[sh][0]*sfni[sh], sfv[sh][1]*sfni[sh]),
                 pk2(sfv[sh][2]*sfni[sh], sfv[sh][3]*sfni[sh]));

    float m2 = mdu[sh]*mdu[sh]+mdu[2+sh]*mdu[2+sh]+mdu[4+sh]*mdu[4+sh];
    float F  = sqrtf(fmaxf(d2s[sh]-128.f*m2, 0.f));
    float Fi = 1.f/fmaxf(F,1e-12f);
    float cx[4],cy[4],cz[4];
#pragma unroll
    for (int r=0;r<4;++r) {
      float ax=adu[sh][r]-mdu[sh], ay=adu[2+sh][r]-mdu[2+sh], az=adu[4+sh][r]-mdu[4+sh];
      float rn = sqrtf(ax*ax+ay*ay+az*az);
      float s1 = (rn*Fi)/fmaxf(rn,1e-12f);
      ax*=s1; ay*=s1; az*=s1;
      float bx=avo[sh][r]-moo[sh], by=avo[2+sh][r]-moo[2+sh], bz=avo[4+sh][r]-moo[4+sh];
      cx[r]=ay*bz-az*by+avo[sh][r];
      cy[r]=az*bx-ax*bz+avo[2+sh][r];
      cz[r]=ax*by-ay*bx+avo[4+sh][r];
    }
    *(uint2*)&bfr[((ksx*6+sh)*64+laneP)*8 + j0]   = make_uint2(pk2(cx[0],cx[1]), pk2(cx[2],cx[3]));
    *(uint2*)&bfr[((ksx*6+2+sh)*64+laneP)*8 + j0] = make_uint2(pk2(cy[0],cy[1]), pk2(cy[2],cy[3]));
    *(uint2*)&bfr[((ksx*6+4+sh)*64+laneP)*8 + j0] = make_uint2(pk2(cz[0],cz[1]), pk2(cz[2],cz[3]));
    *(uint2*)&bfr[(((4+ksx)*6+sh)*64+laneP)*8 + j0]   = make_uint2(pk2(avo[sh][0],avo[sh][1]), pk2(avo[sh][2],avo[sh][3]));
    *(uint2*)&bfr[(((4+ksx)*6+2+sh)*64+laneP)*8 + j0] = make_uint2(pk2(avo[2+sh][0],avo[2+sh][1]), pk2(avo[2+sh][2],avo[2+sh][3]));
    *(uint2*)&bfr[(((4+ksx)*6+4+sh)*64+laneP)*8 + j0] = make_uint2(pk2(avo[4+sh][0],avo[4+sh][1]), pk2(avo[4+sh][2],avo[4+sh][3]));
  }
  __syncthreads(); // B3

  // ---- phase C: crossfc (K=256) + s-path GEMMs ----
  f32x4 afc[6];
#pragma unroll
  for (int nt=0;nt<6;++nt)
    afc[nt]=(f32x4){wsf[128+obase],wsf[128+obase+1],wsf[128+obase+2],wsf[128+obase+3]};
#pragma unroll
  for (int ks=0;ks<8;++ks) {
    bf16x8 a5 = wv[4096 + (w*8+ks)*64 + l];
#pragma unroll
    for (int nt=0;nt<6;++nt)
      afc[nt] = __builtin_amdgcn_mfma_f32_16x16x32_bf16(a5, bv[(ks*6+nt)*64+l], afc[nt], 0,0,0);
  }
#pragma unroll
  for (int nt=0;nt<6;++nt) {
    int d = nt>>1, site = 16*(nt&1)+c15;
#pragma unroll
    for (int r=0;r<4;++r)
      out_v[vbase + (size_t)((obase+r)*3 + d)*4096 + site] = afc[nt][r];
  }
  if (w < 4) {
    f32x4 as2[2];
    as2[0] = (f32x4){vs_b[obase]+ss_b[obase],   vs_b[obase+1]+ss_b[obase+1],
                     vs_b[obase+2]+ss_b[obase+2], vs_b[obase+3]+ss_b[obase+3]};
    as2[1] = as2[0];
#pragma unroll
    for (int ks=0;ks<4;++ks) {
      bf16x8 a6 = wv[11264 + (w*4+ks)*64 + l];
#pragma unroll
      for (int snt=0;snt<2;++snt)
        as2[snt] = __builtin_amdgcn_mfma_f32_16x16x32_bf16(a6, vfv_p[(ks*2+snt)*64+l], as2[snt], 0,0,0);
    }
#pragma unroll
    for (int ks=0;ks<2;++ks) {
      bf16x8 a7 = wv[12288 + (w*2+ks)*64 + l];
#pragma unroll
      for (int snt=0;snt<2;++snt)
        as2[snt] = __builtin_amdgcn_mfma_f32_16x16x32_bf16(a7, sfv_p[(ks*2+snt)*64+l], as2[snt], 0,0,0);
    }
#pragma unroll
    for (int snt=0;snt<2;++snt)
#pragma unroll
      for (int r=0;r<4;++r)
        out_s[sbase + (size_t)(obase+r)*4096 + 16*snt + c15] = as2[snt][r];
  }
}

extern "C" void kernel_launch(void* const* d_in, const int* in_sizes, int n_in,
                              void* d_out, int out_size, void* d_ws, size_t ws_size,
                              hipStream_t stream) {
  (void)in_sizes; (void)n_in; (void)out_size; (void)ws_size;
  const float* v_in      = (const float*)d_in[0];
  const float* s_in      = (const float*)d_in[1];
  const float* weight    = (const float*)d_in[2];
  const float* sv_w      = (const float*)d_in[3];
  const float* sv_b      = (const float*)d_in[4];
  const float* cross_w   = (const float*)d_in[5];
  const float* cross_b   = (const float*)d_in[6];
  const float* crossfc_w = (const float*)d_in[7];
  const float* crossfc_b = (const float*)d_in[8];
  const float* vsdir_w   = (const float*)d_in[9];
  const float* vsdir_b   = (const float*)d_in[10];
  const float* vs_w      = (const float*)d_in[11];
  const float* vs_b      = (const float*)d_in[12];
  const float* ss_w      = (const float*)d_in[13];
  const float* ss_b      = (const float*)d_in[14];

  unsigned short* wsb = (unsigned short*)d_ws;
  float* wsf = (float*)((char*)d_ws + 204800);

  kprep<<<8, 512, 0, stream>>>(weight, sv_w, cross_w, cross_b, crossfc_w, crossfc_b,
                               vsdir_w, vsdir_b, vs_w, ss_w, wsb, wsf);
  dim3 grid(4096/TSB, 8);
  kmain<<<grid, 512, 0, stream>>>(v_in, s_in, sv_b, vs_b, ss_b, wsb, wsf,
                                  (float*)d_out, (float*)d_out + VOUT_ELEMS);
}

// Round 5
// 86.105 us; speedup vs baseline: 7.0510x; 1.0993x over previous
//
#include <hip/hip_runtime.h>

#define VOUT_ELEMS 12582912   // 8*128*3*4096

typedef __attribute__((ext_vector_type(8))) short bf16x8;
typedef __attribute__((ext_vector_type(4))) float f32x4;

__device__ __forceinline__ unsigned short f2b(float f) {
  unsigned x = __float_as_uint(f);
  x = (x + 0x7FFFu + ((x >> 16) & 1u)) >> 16;
  return (unsigned short)x;
}
__device__ __forceinline__ float b2f(unsigned short u) {
  return __uint_as_float(((unsigned)u) << 16);
}
__device__ __forceinline__ unsigned pk2(float a, float b) {
  unsigned r;
  asm("v_cvt_pk_bf16_f32 %0, %1, %2" : "=v"(r) : "v"(a), "v"(b));
  return r;
}

// ws layout (bf16 elems): aW1@0, aW2@16384, aFC@32768, aVD@65536, aSV@81920,
// aVS@90112, aSS@98304. f32 biases at byte 204800: b2n[128], bfcn[128], bdirn[128].

__global__ void kprep(const float* __restrict__ weight, const float* __restrict__ sv_w,
                      const float* __restrict__ cross_w, const float* __restrict__ cross_b,
                      const float* __restrict__ crossfc_w, const float* __restrict__ crossfc_b,
                      const float* __restrict__ vsdir_w, const float* __restrict__ vsdir_b,
                      const float* __restrict__ vs_w, const float* __restrict__ ss_w,
                      unsigned short* __restrict__ wsb, float* __restrict__ wsf)
{
  const int tid = threadIdx.x;           // 512
  const int bid = blockIdx.x;            // 8 blocks
  __shared__ float rs1[128], rs2[128], rsF[128], vdm[128], nrm[3];

  { // parallel row sums: 4 threads per output row
    int o = tid >> 2, part = tid & 3;
    float a = 0.f, b = 0.f, f = 0.f, v = 0.f;
    for (int c = part; c < 127; c += 4) { a += weight[o*127+c]; b += cross_w[o*127+c]; }
    for (int c = part; c < 255; c += 4) f += crossfc_w[o*255+c];
    for (int c = part; c < 128; c += 4) v += vsdir_w[o*128+c];
    a += __shfl_xor(a,1,64); a += __shfl_xor(a,2,64);
    b += __shfl_xor(b,1,64); b += __shfl_xor(b,2,64);
    f += __shfl_xor(f,1,64); f += __shfl_xor(f,2,64);
    v += __shfl_xor(v,1,64); v += __shfl_xor(v,2,64);
    if (part == 0) { rs1[o]=a; rs2[o]=b; rsF[o]=f; vdm[o]=v*(1.f/128.f); }
  }
  if (bid == 0) {
    const float* bsrc = (tid < 64) ? cross_b : (tid < 128 ? crossfc_b : vsdir_b);
    if (tid < 192) {
      int lane = tid & 63;
      float a = 0.f;
      for (int i = lane; i < 128; i += 64) { float t = bsrc[i]; a += t*t; }
      for (int m = 1; m < 64; m <<= 1) a += __shfl_xor(a, m, 64);
      if (lane == 0) nrm[tid >> 6] = sqrtf(a);
    }
  }
  __syncthreads();
  if (bid == 0 && tid < 128) {
    wsf[tid]     = cross_b[tid]   / fmaxf(nrm[0],1e-12f) * 1e-6f;
    wsf[128+tid] = crossfc_b[tid] / fmaxf(nrm[1],1e-12f) * 1e-6f;
    wsf[256+tid] = vsdir_b[tid]   / fmaxf(nrm[2],1e-12f) * 1e-6f;
  }
  const int stride = 512*8;
  const int base = bid*512 + tid;
  for (int i = base; i < 16384; i += stride) {
    int j=i&7, lane=(i>>3)&63, ks=(i>>9)&3, mt=i>>11;
    int o=16*mt+(lane&15), cc=32*ks+8*(lane>>4)+j;
    wsb[i]       = f2b(cc<127 ? weight[o*127+cc]  : 1.f-rs1[o]);
    wsb[16384+i] = f2b(cc<127 ? cross_w[o*127+cc] : 1.f-rs2[o]);
    wsb[65536+i] = f2b(vsdir_w[o*128+cc] - vdm[o]);
  }
  for (int i = base; i < 32768; i += stride) {
    int j=i&7, lane=(i>>3)&63, ks=(i>>9)&7, mt=i>>12;
    int o=16*mt+(lane&15), cc=32*ks+8*(lane>>4)+j;
    wsb[32768+i] = f2b(cc<255 ? crossfc_w[o*255+cc] : 1.f-rsF[o]);
  }
  for (int i = base; i < 8192; i += stride) {
    int j=i&7, lane=(i>>3)&63, ks=(i>>9)&1, mt=i>>10;
    int o=16*mt+(lane&15), s=32*ks+8*(lane>>4)+j;
    wsb[81920+i] = f2b(sv_w[o*64+s]);
  }
  for (int i = base; i < 8192; i += stride) {
    int j=i&7, lane=(i>>3)&63, ks=(i>>9)&3, mt=i>>11;   // mt 0..3
    int o=16*mt+(lane&15), c=32*ks+8*(lane>>4)+j;
    wsb[90112+i] = f2b(vs_w[o*128+c]);
  }
  for (int i = base; i < 4096; i += stride) {
    int j=i&7, lane=(i>>3)&63, ks=(i>>9)&1, mt=i>>10;
    int o=16*mt+(lane&15), s=32*ks+8*(lane>>4)+j;
    wsb[98304+i] = f2b(ss_w[o*64+s]);
  }
}

// 256 threads, 4 waves; 16 sites/block; wave w owns M-tiles mt=w and mt=w+4.
__global__ __launch_bounds__(256, 4) void kmain(
    const float* __restrict__ v_in, const float* __restrict__ s_in,
    const float* __restrict__ sv_b, const float* __restrict__ vs_b,
    const float* __restrict__ ss_b,
    const unsigned short* __restrict__ wsb, const float* __restrict__ wsf,
    float* __restrict__ out_v, float* __restrict__ out_s)
{
  __shared__ unsigned short bfr[12288];  // 24 slots (ks 0..7 x d 0..2) * 64 lanes * 8
  __shared__ unsigned short sfr[1024];   // s-input frags: ks 0..1
  __shared__ unsigned short vfr[2048];   // s_from_v frags: ks 0..3
  __shared__ float gmx[48];              // x channel-mean [d][site]
  __shared__ float gred[8][16][4];       // round-1: pv[3], pd[3], pd2, ps
  __shared__ float gred2[4][16][4];      // round-2: po[3], pfn

  const int tid = threadIdx.x;
  const int w = tid >> 6, l = tid & 63, h = l >> 4, c15 = l & 15;
  const int n0 = blockIdx.x * 16;
  const size_t bb = blockIdx.y;
  const size_t vbase = bb*384*4096 + n0;
  const size_t sbase = bb*64*4096 + n0;

  // ---- phase A: quad-channel pair-packed scatter ----
  for (int i = tid; i < 384; i += 256) {        // (cq 0..31, d 0..2, q 0..3)
    int q = i & 3, d = (i >> 2) % 3, cq = i / 12;
    const float* src = &v_in[vbase + (size_t)(4*cq*3 + d)*4096 + 4*q];
    float4 x0 = *(const float4*)(src);
    float4 x1 = *(const float4*)(src + 3*4096);
    float4 x2 = *(const float4*)(src + 6*4096);
    float4 x3 = *(const float4*)(src + 9*4096);
    int slot = (cq >> 3)*3 + d;
    int hh = (cq >> 1) & 3;
    int jp = 2*(cq & 1);
    unsigned* bp = (unsigned*)bfr + (slot*64 + 16*hh + 4*q)*4 + jp;
    float a0[4]={x0.x,x0.y,x0.z,x0.w}, a1[4]={x1.x,x1.y,x1.z,x1.w};
    float a2[4]={x2.x,x2.y,x2.z,x2.w}, a3[4]={x3.x,x3.y,x3.z,x3.w};
#pragma unroll
    for (int e=0;e<4;++e)
      *(uint2*)(bp + e*4) = make_uint2(pk2(a0[e],a1[e]), pk2(a2[e],a3[e]));
  }
  if (tid < 64) {                               // (sq 0..15, q 0..3)
    int q = tid & 3, sq = tid >> 2;
    const float* src = &s_in[sbase + (size_t)(4*sq)*4096 + 4*q];
    float4 x0 = *(const float4*)(src);
    float4 x1 = *(const float4*)(src + 4096);
    float4 x2 = *(const float4*)(src + 2*4096);
    float4 x3 = *(const float4*)(src + 3*4096);
    int slot = sq >> 3;
    int hh = (sq >> 1) & 3;
    int jp = 2*(sq & 1);
    unsigned* bp = (unsigned*)sfr + (slot*64 + 16*hh + 4*q)*4 + jp;
    float a0[4]={x0.x,x0.y,x0.z,x0.w}, a1[4]={x1.x,x1.y,x1.z,x1.w};
    float a2[4]={x2.x,x2.y,x2.z,x2.w}, a3[4]={x3.x,x3.y,x3.z,x3.w};
#pragma unroll
    for (int e=0;e<4;++e)
      *(uint2*)(bp + e*4) = make_uint2(pk2(a0[e],a1[e]), pk2(a2[e],a3[e]));
  }
  __syncthreads();  // B1

  const bf16x8* bv  = (const bf16x8*)bfr;
  const bf16x8* sfv_p = (const bf16x8*)sfr;
  const bf16x8* vfv_p = (const bf16x8*)vfr;
  const bf16x8* wv  = (const bf16x8*)wsb;
  const int obA = 16*w + 4*h, obB = 16*(w+4) + 4*h;

  // ---- phase B ----
  f32x4 avo[2][3], adu[2][3], adr[2][3], asc[2];
  {
    f32x4 b2A = *(const f32x4*)&wsf[obA],     b2B = *(const f32x4*)&wsf[obB];
    f32x4 bdA = *(const f32x4*)&wsf[256+obA], bdB = *(const f32x4*)&wsf[256+obB];
#pragma unroll
    for (int d=0;d<3;++d) {
      avo[0][d]=(f32x4){0.f,0.f,0.f,0.f}; avo[1][d]=(f32x4){0.f,0.f,0.f,0.f};
      adu[0][d]=b2A; adu[1][d]=b2B;
      adr[0][d]=bdA; adr[1][d]=bdB;
    }
    asc[0] = *(const f32x4*)&sv_b[obA];
    asc[1] = *(const f32x4*)&sv_b[obB];
  }
#pragma unroll
  for (int ks=0;ks<4;++ks) {
    bf16x8 bx[3];
#pragma unroll
    for (int d=0;d<3;++d) bx[d] = bv[(ks*3+d)*64 + l];
#pragma unroll
    for (int mt=0;mt<2;++mt) {
      int fa = (w + 4*mt)*4 + ks;
      bf16x8 a1 = wv[fa*64 + l];
      bf16x8 a2 = wv[2048 + fa*64 + l];
      bf16x8 a3 = wv[8192 + fa*64 + l];
#pragma unroll
      for (int d=0;d<3;++d) {
        avo[mt][d] = __builtin_amdgcn_mfma_f32_16x16x32_bf16(a1, bx[d], avo[mt][d], 0,0,0);
        adu[mt][d] = __builtin_amdgcn_mfma_f32_16x16x32_bf16(a2, bx[d], adu[mt][d], 0,0,0);
        adr[mt][d] = __builtin_amdgcn_mfma_f32_16x16x32_bf16(a3, bx[d], adr[mt][d], 0,0,0);
      }
    }
  }
#pragma unroll
  for (int ks=0;ks<2;++ks) {
    bf16x8 bs = sfv_p[ks*64 + l];
#pragma unroll
    for (int mt=0;mt<2;++mt) {
      bf16x8 a4 = wv[10240 + ((w+4*mt)*2+ks)*64 + l];
      asc[mt] = __builtin_amdgcn_mfma_f32_16x16x32_bf16(a4, bs, asc[mt], 0,0,0);
    }
  }
  if (w < 3) {  // x channel-mean via ones-row GEMV; wave w handles d=w
    bf16x8 aone;
#pragma unroll
    for (int j=0;j<8;++j) aone[j] = (short)0x3C00;  // bf16(1/128)
    f32x4 amx = (f32x4){0.f,0.f,0.f,0.f};
#pragma unroll
    for (int ks=0;ks<4;++ks)
      amx = __builtin_amdgcn_mfma_f32_16x16x32_bf16(aone, bv[(ks*3+w)*64+l], amx, 0,0,0);
    if (h==0) gmx[16*w + c15] = amx[0];
  }

  // ---- round-1 reductions ----
  {
    float red[8];
#pragma unroll
    for (int d=0;d<3;++d) {
      red[d]   = avo[0][d][0]+avo[0][d][1]+avo[0][d][2]+avo[0][d][3]
               + avo[1][d][0]+avo[1][d][1]+avo[1][d][2]+avo[1][d][3];
      red[3+d] = adu[0][d][0]+adu[0][d][1]+adu[0][d][2]+adu[0][d][3]
               + adu[1][d][0]+adu[1][d][1]+adu[1][d][2]+adu[1][d][3];
    }
    float q2 = 0.f;
#pragma unroll
    for (int mt=0;mt<2;++mt)
#pragma unroll
      for (int d=0;d<3;++d)
#pragma unroll
        for (int r=0;r<4;++r) q2 += adu[mt][d][r]*adu[mt][d][r];
    red[6] = q2;
    red[7] = asc[0][0]*asc[0][0]+asc[0][1]*asc[0][1]+asc[0][2]*asc[0][2]+asc[0][3]*asc[0][3]
           + asc[1][0]*asc[1][0]+asc[1][1]*asc[1][1]+asc[1][2]*asc[1][2]+asc[1][3]*asc[1][3];
#pragma unroll
    for (int m=16;m<64;m<<=1)
#pragma unroll
      for (int i=0;i<8;++i) red[i] += __shfl_xor(red[i], m, 64);
    if (h==0)
#pragma unroll
      for (int i=0;i<8;++i) gred[i][c15][w] = red[i];
  }
  __syncthreads(); // B2

  float mvo[3], mdu[3], mxv[3], d2s, sinv;
#pragma unroll
  for (int d=0;d<3;++d) {
    f32x4 t = *(const f32x4*)gred[d][c15];
    f32x4 u = *(const f32x4*)gred[3+d][c15];
    mvo[d] = (t[0]+t[1]+t[2]+t[3]) * (1.f/128.f);
    mdu[d] = (u[0]+u[1]+u[2]+u[3]) * (1.f/128.f);
    mxv[d] = gmx[16*d + c15];
  }
  { f32x4 t = *(const f32x4*)gred[6][c15]; d2s = t[0]+t[1]+t[2]+t[3]; }
  { f32x4 t = *(const f32x4*)gred[7][c15];
    sinv = 1.f / fmaxf(sqrtf(t[0]+t[1]+t[2]+t[3]), 1e-12f); }

  // apply invariant scale; po partials
  float po[3] = {0.f,0.f,0.f};
#pragma unroll
  for (int mt=0;mt<2;++mt)
#pragma unroll
    for (int r=0;r<4;++r) {
      float sk = asc[mt][r] * sinv;
#pragma unroll
      for (int d=0;d<3;++d) {
        float t = (avo[mt][d][r]-mvo[d])*sk + mvo[d];
        avo[mt][d][r] = t;
        po[d] += t;
      }
    }

  // v_sR readback + dir-normalized invariant dot
  float sfvv[2][4]; float pfn = 0.f;
#pragma unroll
  for (int mt=0;mt<2;++mt) {
    int c0 = 16*(w+4*mt) + 4*h;
    int ks = c0 >> 5, hh = (c0>>3)&3, ju = 2*(h&1);
    float xr[3][4];
#pragma unroll
    for (int d=0;d<3;++d) {
      uint2 u = *(const uint2*)((const unsigned*)bfr + ((ks*3+d)*64 + 16*hh + c15)*4 + ju);
      xr[d][0]=b2f((unsigned short)u.x);  xr[d][1]=b2f((unsigned short)(u.x>>16));
      xr[d][2]=b2f((unsigned short)u.y);  xr[d][3]=b2f((unsigned short)(u.y>>16));
    }
#pragma unroll
    for (int r=0;r<4;++r) {
      float dx=adr[mt][0][r], dy=adr[mt][1][r], dz=adr[mt][2][r];
      float rn = sqrtf(dx*dx+dy*dy+dz*dz);
      float inv = 1.f/fmaxf(rn,1e-12f);
      float vx = xr[0][r]-mxv[0], vy = xr[1][r]-mxv[1], vz = xr[2][r]-mxv[2];
      float dot = (vx*dx+vy*dy+vz*dz)*inv;
      sfvv[mt][r] = dot; pfn += dot*dot;
    }
  }

  // ---- round-2 reductions ----
  {
    float red2[4] = {po[0], po[1], po[2], pfn};
#pragma unroll
    for (int m=16;m<64;m<<=1)
#pragma unroll
      for (int i=0;i<4;++i) red2[i] += __shfl_xor(red2[i], m, 64);
    if (h==0)
#pragma unroll
      for (int i=0;i<4;++i) gred2[i][c15][w] = red2[i];
  }
  __syncthreads(); // B2b

  float moo[3], sfni;
#pragma unroll
  for (int d=0;d<3;++d) {
    f32x4 t = *(const f32x4*)gred2[d][c15];
    moo[d] = (t[0]+t[1]+t[2]+t[3]) * (1.f/128.f);
  }
  { f32x4 t = *(const f32x4*)gred2[3][c15];
    sfni = 1.f/fmaxf(sqrtf(t[0]+t[1]+t[2]+t[3]), 1e-12f); }

  // cross-product + fragment writes (own channels only)
  float m2 = mdu[0]*mdu[0]+mdu[1]*mdu[1]+mdu[2]*mdu[2];
  float F  = sqrtf(fmaxf(d2s - 128.f*m2, 0.f));
  float Fi = 1.f/fmaxf(F, 1e-12f);
#pragma unroll
  for (int mt=0;mt<2;++mt) {
    int c0 = 16*(w+4*mt) + 4*h;
    int ks = c0 >> 5, hh = (c0>>3)&3, ju = 2*(h&1);
    *(uint2*)((unsigned*)vfr + (ks*64 + 16*hh + c15)*4 + ju) =
      make_uint2(pk2(sfvv[mt][0]*sfni, sfvv[mt][1]*sfni),
                 pk2(sfvv[mt][2]*sfni, sfvv[mt][3]*sfni));
    float cv[3][4];
#pragma unroll
    for (int r=0;r<4;++r) {
      float ax=adu[mt][0][r]-mdu[0], ay=adu[mt][1][r]-mdu[1], az=adu[mt][2][r]-mdu[2];
      float rn = sqrtf(ax*ax+ay*ay+az*az);
      float s1 = (rn*Fi)/fmaxf(rn,1e-12f);
      ax*=s1; ay*=s1; az*=s1;
      float bx=avo[mt][0][r]-moo[0], by=avo[mt][1][r]-moo[1], bz=avo[mt][2][r]-moo[2];
      cv[0][r]=ay*bz-az*by+avo[mt][0][r];
      cv[1][r]=az*bx-ax*bz+avo[mt][1][r];
      cv[2][r]=ax*by-ay*bx+avo[mt][2][r];
    }
#pragma unroll
    for (int d=0;d<3;++d) {
      *(uint2*)((unsigned*)bfr + ((ks*3+d)*64 + 16*hh + c15)*4 + ju) =
        make_uint2(pk2(cv[d][0],cv[d][1]), pk2(cv[d][2],cv[d][3]));
      *(uint2*)((unsigned*)bfr + (((4+ks)*3+d)*64 + 16*hh + c15)*4 + ju) =
        make_uint2(pk2(avo[mt][d][0],avo[mt][d][1]), pk2(avo[mt][d][2],avo[mt][d][3]));
    }
  }
  __syncthreads(); // B3

  // ---- phase C: crossfc (K=256) + s-path GEMMs ----
  f32x4 afc[2][3];
  {
    f32x4 bfA = *(const f32x4*)&wsf[128+obA], bfB = *(const f32x4*)&wsf[128+obB];
#pragma unroll
    for (int d=0;d<3;++d) { afc[0][d]=bfA; afc[1][d]=bfB; }
  }
#pragma unroll
  for (int ks=0;ks<8;++ks) {
    bf16x8 bx[3];
#pragma unroll
    for (int d=0;d<3;++d) bx[d] = bv[(ks*3+d)*64 + l];
#pragma unroll
    for (int mt=0;mt<2;++mt) {
      bf16x8 a5 = wv[4096 + ((w+4*mt)*8+ks)*64 + l];
#pragma unroll
      for (int d=0;d<3;++d)
        afc[mt][d] = __builtin_amdgcn_mfma_f32_16x16x32_bf16(a5, bx[d], afc[mt][d], 0,0,0);
    }
  }
  f32x4 as2;
  {
    f32x4 bv1 = *(const f32x4*)&vs_b[obA];
    f32x4 bv2 = *(const f32x4*)&ss_b[obA];
    as2 = (f32x4){bv1[0]+bv2[0], bv1[1]+bv2[1], bv1[2]+bv2[2], bv1[3]+bv2[3]};
  }
#pragma unroll
  for (int ks=0;ks<4;++ks) {
    bf16x8 a6 = wv[11264 + (w*4+ks)*64 + l];
    as2 = __builtin_amdgcn_mfma_f32_16x16x32_bf16(a6, vfv_p[ks*64+l], as2, 0,0,0);
  }
#pragma unroll
  for (int ks=0;ks<2;++ks) {
    bf16x8 a7 = wv[12288 + (w*2+ks)*64 + l];
    as2 = __builtin_amdgcn_mfma_f32_16x16x32_bf16(a7, sfv_p[ks*64+l], as2, 0,0,0);
  }

  // ---- epilogue: direct global stores ----
#pragma unroll
  for (int mt=0;mt<2;++mt) {
    int c0 = 16*(w+4*mt) + 4*h;
#pragma unroll
    for (int d=0;d<3;++d)
#pragma unroll
      for (int r=0;r<4;++r)
        out_v[vbase + (size_t)((c0+r)*3 + d)*4096 + c15] = afc[mt][d][r];
  }
#pragma unroll
  for (int r=0;r<4;++r)
    out_s[sbase + (size_t)(obA+r)*4096 + c15] = as2[r];
}

extern "C" void kernel_launch(void* const* d_in, const int* in_sizes, int n_in,
                              void* d_out, int out_size, void* d_ws, size_t ws_size,
                              hipStream_t stream) {
  (void)in_sizes; (void)n_in; (void)out_size; (void)ws_size;
  const float* v_in      = (const float*)d_in[0];
  const float* s_in      = (const float*)d_in[1];
  const float* weight    = (const float*)d_in[2];
  const float* sv_w      = (const float*)d_in[3];
  const float* sv_b      = (const float*)d_in[4];
  const float* cross_w   = (const float*)d_in[5];
  const float* cross_b   = (const float*)d_in[6];
  const float* crossfc_w = (const float*)d_in[7];
  const float* crossfc_b = (const float*)d_in[8];
  const float* vsdir_w   = (const float*)d_in[9];
  const float* vsdir_b   = (const float*)d_in[10];
  const float* vs_w      = (const float*)d_in[11];
  const float* vs_b      = (const float*)d_in[12];
  const float* ss_w      = (const float*)d_in[13];
  const float* ss_b      = (const float*)d_in[14];

  unsigned short* wsb = (unsigned short*)d_ws;
  float* wsf = (float*)((char*)d_ws + 204800);

  kprep<<<8, 512, 0, stream>>>(weight, sv_w, cross_w, cross_b, crossfc_w, crossfc_b,
                               vsdir_w, vsdir_b, vs_w, ss_w, wsb, wsf);
  dim3 grid(4096/16, 8);
  kmain<<<grid, 256, 0, stream>>>(v_in, s_in, sv_b, vs_b, ss_b, wsb, wsf,
                                  (float*)d_out, (float*)d_out + VOUT_ELEMS);
}

// Round 6
// 64.314 us; speedup vs baseline: 9.4399x; 1.3388x over previous
//
#include <hip/hip_runtime.h>

#define VOUT_ELEMS 12582912   // 8*128*3*4096

typedef __attribute__((ext_vector_type(8))) short bf16x8;
typedef __attribute__((ext_vector_type(4))) float f32x4;

__device__ __forceinline__ unsigned short f2b(float f) {
  unsigned x = __float_as_uint(f);
  x = (x + 0x7FFFu + ((x >> 16) & 1u)) >> 16;
  return (unsigned short)x;
}
__device__ __forceinline__ float b2f(unsigned short u) {
  return __uint_as_float(((unsigned)u) << 16);
}
__device__ __forceinline__ unsigned pk2(float a, float b) {
  unsigned r;
  asm("v_cvt_pk_bf16_f32 %0, %1, %2" : "=v"(r) : "v"(a), "v"(b));
  return r;
}

// ws layout (bf16 elems): aW1@0, aW2@16384, aFC@32768, aVD@65536, aSV@81920,
// aVS@90112, aSS@98304.
// f32 at byte 204800 (wsf): [0:128) b2n, [128:256) bfcn, [256:384) bdirn,
// [384:512) rs1, [512:640) rs2, [640:768) rsF, [768:896) vdm (already /128).

// ---- kprep0: row sums (wave-per-row, coalesced) + normalized eps-biases ----
__global__ void kprep0(const float* __restrict__ weight, const float* __restrict__ cross_w,
                       const float* __restrict__ crossfc_w, const float* __restrict__ vsdir_w,
                       const float* __restrict__ cross_b, const float* __restrict__ crossfc_b,
                       const float* __restrict__ vsdir_b, float* __restrict__ wsf)
{
  const int tid = threadIdx.x;              // 256
  const int l = tid & 63;
  const int wg = blockIdx.x*4 + (tid>>6);   // 0..63, 2 rows each
#pragma unroll
  for (int k = 0; k < 2; ++k) {
    int o = wg*2 + k;
    float a = weight[o*127+l]  + ((l<63) ? weight[o*127+64+l]  : 0.f);
    float b = cross_w[o*127+l] + ((l<63) ? cross_w[o*127+64+l] : 0.f);
    float f = crossfc_w[o*255+l] + crossfc_w[o*255+64+l] + crossfc_w[o*255+128+l]
            + ((l<63) ? crossfc_w[o*255+192+l] : 0.f);
    float v = vsdir_w[o*128+l] + vsdir_w[o*128+64+l];
#pragma unroll
    for (int m = 1; m < 64; m <<= 1) {
      a += __shfl_xor(a,m,64); b += __shfl_xor(b,m,64);
      f += __shfl_xor(f,m,64); v += __shfl_xor(v,m,64);
    }
    if (l == 0) {
      wsf[384+o] = a; wsf[512+o] = b; wsf[640+o] = f; wsf[768+o] = v*(1.f/128.f);
    }
  }
  if (blockIdx.x == 0 && tid < 192) {
    const float* bsrc = (tid < 64) ? cross_b : (tid < 128 ? crossfc_b : vsdir_b);
    float a = 0.f;
    for (int i = l; i < 128; i += 64) { float t = bsrc[i]; a += t*t; }
#pragma unroll
    for (int m = 1; m < 64; m <<= 1) a += __shfl_xor(a,m,64);
    float nb = fmaxf(sqrtf(a), 1e-12f);
    for (int i = l; i < 128; i += 64)
      wsf[(tid>>6)*128 + i] = bsrc[i] / nb * 1e-6f;
  }
}

// ---- kprep1: pack completed+transposed weights into MFMA A-fragments ----
__global__ void kprep1(const float* __restrict__ weight, const float* __restrict__ sv_w,
                       const float* __restrict__ cross_w, const float* __restrict__ crossfc_w,
                       const float* __restrict__ vsdir_w, const float* __restrict__ vs_w,
                       const float* __restrict__ ss_w,
                       unsigned short* __restrict__ wsb, const float* __restrict__ wsf)
{
  const int stride = 64*256;
  const int base = blockIdx.x*256 + threadIdx.x;
  const float* rs1 = wsf+384; const float* rs2 = wsf+512;
  const float* rsF = wsf+640; const float* vdm = wsf+768;
  for (int i = base; i < 16384; i += stride) {
    int j=i&7, lane=(i>>3)&63, ks=(i>>9)&3, mt=i>>11;
    int o=16*mt+(lane&15), cc=32*ks+8*(lane>>4)+j;
    wsb[i]       = f2b(cc<127 ? weight[o*127+cc]  : 1.f-rs1[o]);
    wsb[16384+i] = f2b(cc<127 ? cross_w[o*127+cc] : 1.f-rs2[o]);
    wsb[65536+i] = f2b(vsdir_w[o*128+cc] - vdm[o]);
  }
  for (int i = base; i < 32768; i += stride) {
    int j=i&7, lane=(i>>3)&63, ks=(i>>9)&7, mt=i>>12;
    int o=16*mt+(lane&15), cc=32*ks+8*(lane>>4)+j;
    wsb[32768+i] = f2b(cc<255 ? crossfc_w[o*255+cc] : 1.f-rsF[o]);
  }
  for (int i = base; i < 8192; i += stride) {
    int j=i&7, lane=(i>>3)&63, ks=(i>>9)&1, mt=i>>10;
    int o=16*mt+(lane&15), s=32*ks+8*(lane>>4)+j;
    wsb[81920+i] = f2b(sv_w[o*64+s]);
  }
  for (int i = base; i < 8192; i += stride) {
    int j=i&7, lane=(i>>3)&63, ks=(i>>9)&3, mt=i>>11;
    int o=16*mt+(lane&15), c=32*ks+8*(lane>>4)+j;
    wsb[90112+i] = f2b(vs_w[o*128+c]);
  }
  for (int i = base; i < 4096; i += stride) {
    int j=i&7, lane=(i>>3)&63, ks=(i>>9)&1, mt=i>>10;
    int o=16*mt+(lane&15), s=32*ks+8*(lane>>4)+j;
    wsb[98304+i] = f2b(ss_w[o*64+s]);
  }
}

// 256 threads, 4 waves; 16 sites/block; wave w owns M-tiles mt=w and mt=w+4.
// LDS 31 KB -> 5 blocks/CU. gmx+gred alias bfr's xo-slot region (slots 12..23):
// gmx/gred are written/read strictly before barrier B2b; xo slots are written
// strictly after B2b (stage-3) -- alias is fenced by B2b.
__global__ __launch_bounds__(256, 4) void kmain(
    const float* __restrict__ v_in, const float* __restrict__ s_in,
    const float* __restrict__ sv_b, const float* __restrict__ vs_b,
    const float* __restrict__ ss_b,
    const unsigned short* __restrict__ wsb, const float* __restrict__ wsf,
    float* __restrict__ out_v, float* __restrict__ out_s)
{
  __shared__ __align__(16) unsigned char smem[31744];
  unsigned short* bfr = (unsigned short*)smem;                  // 24576 B, slots 0..23
  float* gmx          = (float*)(smem + 12288);                 // 192 B   (alias slot 12)
  float (*gred)[16][4]  = (float(*)[16][4])(smem + 12480);      // 2048 B  (alias slots 12..14)
  unsigned short* sfr = (unsigned short*)(smem + 24576);        // 2048 B
  unsigned short* vfr = (unsigned short*)(smem + 26624);        // 4096 B
  float (*gred2)[16][4] = (float(*)[16][4])(smem + 30720);      // 1024 B

  const int tid = threadIdx.x;
  const int w = tid >> 6, l = tid & 63, h = l >> 4, c15 = l & 15;
  const int n0 = blockIdx.x * 16;
  const size_t bb = blockIdx.y;
  const size_t vbase = bb*384*4096 + n0;
  const size_t sbase = bb*64*4096 + n0;

  // ---- phase A: quad-channel pair-packed scatter ----
  for (int i = tid; i < 384; i += 256) {        // (cq 0..31, d 0..2, q 0..3)
    int q = i & 3, d = (i >> 2) % 3, cq = i / 12;
    const float* src = &v_in[vbase + (size_t)(4*cq*3 + d)*4096 + 4*q];
    float4 x0 = *(const float4*)(src);
    float4 x1 = *(const float4*)(src + 3*4096);
    float4 x2 = *(const float4*)(src + 6*4096);
    float4 x3 = *(const float4*)(src + 9*4096);
    int slot = (cq >> 3)*3 + d;
    int hh = (cq >> 1) & 3;
    int jp = 2*(cq & 1);
    unsigned* bp = (unsigned*)bfr + (slot*64 + 16*hh + 4*q)*4 + jp;
    float a0[4]={x0.x,x0.y,x0.z,x0.w}, a1[4]={x1.x,x1.y,x1.z,x1.w};
    float a2[4]={x2.x,x2.y,x2.z,x2.w}, a3[4]={x3.x,x3.y,x3.z,x3.w};
#pragma unroll
    for (int e=0;e<4;++e)
      *(uint2*)(bp + e*4) = make_uint2(pk2(a0[e],a1[e]), pk2(a2[e],a3[e]));
  }
  if (tid < 64) {                               // (sq 0..15, q 0..3)
    int q = tid & 3, sq = tid >> 2;
    const float* src = &s_in[sbase + (size_t)(4*sq)*4096 + 4*q];
    float4 x0 = *(const float4*)(src);
    float4 x1 = *(const float4*)(src + 4096);
    float4 x2 = *(const float4*)(src + 2*4096);
    float4 x3 = *(const float4*)(src + 3*4096);
    int slot = sq >> 3;
    int hh = (sq >> 1) & 3;
    int jp = 2*(sq & 1);
    unsigned* bp = (unsigned*)sfr + (slot*64 + 16*hh + 4*q)*4 + jp;
    float a0[4]={x0.x,x0.y,x0.z,x0.w}, a1[4]={x1.x,x1.y,x1.z,x1.w};
    float a2[4]={x2.x,x2.y,x2.z,x2.w}, a3[4]={x3.x,x3.y,x3.z,x3.w};
#pragma unroll
    for (int e=0;e<4;++e)
      *(uint2*)(bp + e*4) = make_uint2(pk2(a0[e],a1[e]), pk2(a2[e],a3[e]));
  }
  __syncthreads();  // B1

  const bf16x8* bv  = (const bf16x8*)bfr;
  const bf16x8* sfv_p = (const bf16x8*)sfr;
  const bf16x8* vfv_p = (const bf16x8*)vfr;
  const bf16x8* wv  = (const bf16x8*)wsb;
  const int obA = 16*w + 4*h, obB = 16*(w+4) + 4*h;

  // ---- phase B ----
  f32x4 avo[2][3], adu[2][3], adr[2][3], asc[2];
  {
    f32x4 b2A = *(const f32x4*)&wsf[obA],     b2B = *(const f32x4*)&wsf[obB];
    f32x4 bdA = *(const f32x4*)&wsf[256+obA], bdB = *(const f32x4*)&wsf[256+obB];
#pragma unroll
    for (int d=0;d<3;++d) {
      avo[0][d]=(f32x4){0.f,0.f,0.f,0.f}; avo[1][d]=(f32x4){0.f,0.f,0.f,0.f};
      adu[0][d]=b2A; adu[1][d]=b2B;
      adr[0][d]=bdA; adr[1][d]=bdB;
    }
    asc[0] = *(const f32x4*)&sv_b[obA];
    asc[1] = *(const f32x4*)&sv_b[obB];
  }
#pragma unroll
  for (int ks=0;ks<4;++ks) {
    bf16x8 bx[3];
#pragma unroll
    for (int d=0;d<3;++d) bx[d] = bv[(ks*3+d)*64 + l];
#pragma unroll
    for (int mt=0;mt<2;++mt) {
      int fa = (w + 4*mt)*4 + ks;
      bf16x8 a1 = wv[fa*64 + l];
      bf16x8 a2 = wv[2048 + fa*64 + l];
      bf16x8 a3 = wv[8192 + fa*64 + l];
#pragma unroll
      for (int d=0;d<3;++d) {
        avo[mt][d] = __builtin_amdgcn_mfma_f32_16x16x32_bf16(a1, bx[d], avo[mt][d], 0,0,0);
        adu[mt][d] = __builtin_amdgcn_mfma_f32_16x16x32_bf16(a2, bx[d], adu[mt][d], 0,0,0);
        adr[mt][d] = __builtin_amdgcn_mfma_f32_16x16x32_bf16(a3, bx[d], adr[mt][d], 0,0,0);
      }
    }
  }
#pragma unroll
  for (int ks=0;ks<2;++ks) {
    bf16x8 bs = sfv_p[ks*64 + l];
#pragma unroll
    for (int mt=0;mt<2;++mt) {
      bf16x8 a4 = wv[10240 + ((w+4*mt)*2+ks)*64 + l];
      asc[mt] = __builtin_amdgcn_mfma_f32_16x16x32_bf16(a4, bs, asc[mt], 0,0,0);
    }
  }
  if (w < 3) {  // x channel-mean via ones-row GEMV; wave w handles d=w
    bf16x8 aone;
#pragma unroll
    for (int j=0;j<8;++j) aone[j] = (short)0x3C00;  // bf16(1/128)
    f32x4 amx = (f32x4){0.f,0.f,0.f,0.f};
#pragma unroll
    for (int ks=0;ks<4;++ks)
      amx = __builtin_amdgcn_mfma_f32_16x16x32_bf16(aone, bv[(ks*3+w)*64+l], amx, 0,0,0);
    if (h==0) gmx[16*w + c15] = amx[0];
  }

  // ---- round-1 reductions ----
  {
    float red[8];
#pragma unroll
    for (int d=0;d<3;++d) {
      red[d]   = avo[0][d][0]+avo[0][d][1]+avo[0][d][2]+avo[0][d][3]
               + avo[1][d][0]+avo[1][d][1]+avo[1][d][2]+avo[1][d][3];
      red[3+d] = adu[0][d][0]+adu[0][d][1]+adu[0][d][2]+adu[0][d][3]
               + adu[1][d][0]+adu[1][d][1]+adu[1][d][2]+adu[1][d][3];
    }
    float q2 = 0.f;
#pragma unroll
    for (int mt=0;mt<2;++mt)
#pragma unroll
      for (int d=0;d<3;++d)
#pragma unroll
        for (int r=0;r<4;++r) q2 += adu[mt][d][r]*adu[mt][d][r];
    red[6] = q2;
    red[7] = asc[0][0]*asc[0][0]+asc[0][1]*asc[0][1]+asc[0][2]*asc[0][2]+asc[0][3]*asc[0][3]
           + asc[1][0]*asc[1][0]+asc[1][1]*asc[1][1]+asc[1][2]*asc[1][2]+asc[1][3]*asc[1][3];
#pragma unroll
    for (int m=16;m<64;m<<=1)
#pragma unroll
      for (int i=0;i<8;++i) red[i] += __shfl_xor(red[i], m, 64);
    if (h==0)
#pragma unroll
      for (int i=0;i<8;++i) gred[i][c15][w] = red[i];
  }
  __syncthreads(); // B2

  float mvo[3], mdu[3], mxv[3], d2s, sinv;
#pragma unroll
  for (int d=0;d<3;++d) {
    f32x4 t = *(const f32x4*)gred[d][c15];
    f32x4 u = *(const f32x4*)gred[3+d][c15];
    mvo[d] = (t[0]+t[1]+t[2]+t[3]) * (1.f/128.f);
    mdu[d] = (u[0]+u[1]+u[2]+u[3]) * (1.f/128.f);
    mxv[d] = gmx[16*d + c15];
  }
  { f32x4 t = *(const f32x4*)gred[6][c15]; d2s = t[0]+t[1]+t[2]+t[3]; }
  { f32x4 t = *(const f32x4*)gred[7][c15];
    sinv = 1.f / fmaxf(sqrtf(t[0]+t[1]+t[2]+t[3]), 1e-12f); }

  // apply invariant scale; po partials
  float po[3] = {0.f,0.f,0.f};
#pragma unroll
  for (int mt=0;mt<2;++mt)
#pragma unroll
    for (int r=0;r<4;++r) {
      float sk = asc[mt][r] * sinv;
#pragma unroll
      for (int d=0;d<3;++d) {
        float t = (avo[mt][d][r]-mvo[d])*sk + mvo[d];
        avo[mt][d][r] = t;
        po[d] += t;
      }
    }

  // v_sR readback + dir-normalized invariant dot
  float sfvv[2][4]; float pfn = 0.f;
#pragma unroll
  for (int mt=0;mt<2;++mt) {
    int c0 = 16*(w+4*mt) + 4*h;
    int ks = c0 >> 5, hh = (c0>>3)&3, ju = 2*(h&1);
    float xr[3][4];
#pragma unroll
    for (int d=0;d<3;++d) {
      uint2 u = *(const uint2*)((const unsigned*)bfr + ((ks*3+d)*64 + 16*hh + c15)*4 + ju);
      xr[d][0]=b2f((unsigned short)u.x);  xr[d][1]=b2f((unsigned short)(u.x>>16));
      xr[d][2]=b2f((unsigned short)u.y);  xr[d][3]=b2f((unsigned short)(u.y>>16));
    }
#pragma unroll
    for (int r=0;r<4;++r) {
      float dx=adr[mt][0][r], dy=adr[mt][1][r], dz=adr[mt][2][r];
      float rn = sqrtf(dx*dx+dy*dy+dz*dz);
      float inv = 1.f/fmaxf(rn,1e-12f);
      float vx = xr[0][r]-mxv[0], vy = xr[1][r]-mxv[1], vz = xr[2][r]-mxv[2];
      float dot = (vx*dx+vy*dy+vz*dz)*inv;
      sfvv[mt][r] = dot; pfn += dot*dot;
    }
  }

  // ---- round-2 reductions ----
  {
    float red2[4] = {po[0], po[1], po[2], pfn};
#pragma unroll
    for (int m=16;m<64;m<<=1)
#pragma unroll
      for (int i=0;i<4;++i) red2[i] += __shfl_xor(red2[i], m, 64);
    if (h==0)
#pragma unroll
      for (int i=0;i<4;++i) gred2[i][c15][w] = red2[i];
  }
  __syncthreads(); // B2b

  float moo[3], sfni;
#pragma unroll
  for (int d=0;d<3;++d) {
    f32x4 t = *(const f32x4*)gred2[d][c15];
    moo[d] = (t[0]+t[1]+t[2]+t[3]) * (1.f/128.f);
  }
  { f32x4 t = *(const f32x4*)gred2[3][c15];
    sfni = 1.f/fmaxf(sqrtf(t[0]+t[1]+t[2]+t[3]), 1e-12f); }

  // cross-product + fragment writes (own channels only)
  float m2 = mdu[0]*mdu[0]+mdu[1]*mdu[1]+mdu[2]*mdu[2];
  float F  = sqrtf(fmaxf(d2s - 128.f*m2, 0.f));
  float Fi = 1.f/fmaxf(F, 1e-12f);
#pragma unroll
  for (int mt=0;mt<2;++mt) {
    int c0 = 16*(w+4*mt) + 4*h;
    int ks = c0 >> 5, hh = (c0>>3)&3, ju = 2*(h&1);
    *(uint2*)((unsigned*)vfr + (ks*64 + 16*hh + c15)*4 + ju) =
      make_uint2(pk2(sfvv[mt][0]*sfni, sfvv[mt][1]*sfni),
                 pk2(sfvv[mt][2]*sfni, sfvv[mt][3]*sfni));
    float cv[3][4];
#pragma unroll
    for (int r=0;r<4;++r) {
      float ax=adu[mt][0][r]-mdu[0], ay=adu[mt][1][r]-mdu[1], az=adu[mt][2][r]-mdu[2];
      float rn = sqrtf(ax*ax+ay*ay+az*az);
      float s1 = (rn*Fi)/fmaxf(rn,1e-12f);
      ax*=s1; ay*=s1; az*=s1;
      float bx=avo[mt][0][r]-moo[0], by=avo[mt][1][r]-moo[1], bz=avo[mt][2][r]-moo[2];
      cv[0][r]=ay*bz-az*by+avo[mt][0][r];
      cv[1][r]=az*bx-ax*bz+avo[mt][1][r];
      cv[2][r]=ax*by-ay*bx+avo[mt][2][r];
    }
#pragma unroll
    for (int d=0;d<3;++d) {
      *(uint2*)((unsigned*)bfr + ((ks*3+d)*64 + 16*hh + c15)*4 + ju) =
        make_uint2(pk2(cv[d][0],cv[d][1]), pk2(cv[d][2],cv[d][3]));
      *(uint2*)((unsigned*)bfr + (((4+ks)*3+d)*64 + 16*hh + c15)*4 + ju) =
        make_uint2(pk2(avo[mt][d][0],avo[mt][d][1]), pk2(avo[mt][d][2],avo[mt][d][3]));
    }
  }
  __syncthreads(); // B3

  // ---- phase C: crossfc (K=256) + s-path GEMMs ----
  f32x4 afc[2][3];
  {
    f32x4 bfA = *(const f32x4*)&wsf[128+obA], bfB = *(const f32x4*)&wsf[128+obB];
#pragma unroll
    for (int d=0;d<3;++d) { afc[0][d]=bfA; afc[1][d]=bfB; }
  }
#pragma unroll
  for (int ks=0;ks<8;++ks) {
    bf16x8 bx[3];
#pragma unroll
    for (int d=0;d<3;++d) bx[d] = bv[(ks*3+d)*64 + l];
#pragma unroll
    for (int mt=0;mt<2;++mt) {
      bf16x8 a5 = wv[4096 + ((w+4*mt)*8+ks)*64 + l];
#pragma unroll
      for (int d=0;d<3;++d)
        afc[mt][d] = __builtin_amdgcn_mfma_f32_16x16x32_bf16(a5, bx[d], afc[mt][d], 0,0,0);
    }
  }
  f32x4 as2;
  {
    f32x4 bv1 = *(const f32x4*)&vs_b[obA];
    f32x4 bv2 = *(const f32x4*)&ss_b[obA];
    as2 = (f32x4){bv1[0]+bv2[0], bv1[1]+bv2[1], bv1[2]+bv2[2], bv1[3]+bv2[3]};
  }
#pragma unroll
  for (int ks=0;ks<4;++ks) {
    bf16x8 a6 = wv[11264 + (w*4+ks)*64 + l];
    as2 = __builtin_amdgcn_mfma_f32_16x16x32_bf16(a6, vfv_p[ks*64+l], as2, 0,0,0);
  }
#pragma unroll
  for (int ks=0;ks<2;++ks) {
    bf16x8 a7 = wv[12288 + (w*2+ks)*64 + l];
    as2 = __builtin_amdgcn_mfma_f32_16x16x32_bf16(a7, sfv_p[ks*64+l], as2, 0,0,0);
  }

  // ---- epilogue: direct global stores ----
#pragma unroll
  for (int mt=0;mt<2;++mt) {
    int c0 = 16*(w+4*mt) + 4*h;
#pragma unroll
    for (int d=0;d<3;++d)
#pragma unroll
      for (int r=0;r<4;++r)
        out_v[vbase + (size_t)((c0+r)*3 + d)*4096 + c15] = afc[mt][d][r];
  }
#pragma unroll
  for (int r=0;r<4;++r)
    out_s[sbase + (size_t)(obA+r)*4096 + c15] = as2[r];
}

extern "C" void kernel_launch(void* const* d_in, const int* in_sizes, int n_in,
                              void* d_out, int out_size, void* d_ws, size_t ws_size,
                              hipStream_t stream) {
  (void)in_sizes; (void)n_in; (void)out_size; (void)ws_size;
  const float* v_in      = (const float*)d_in[0];
  const float* s_in      = (const float*)d_in[1];
  const float* weight    = (const float*)d_in[2];
  const float* sv_w      = (const float*)d_in[3];
  const float* sv_b      = (const float*)d_in[4];
  const float* cross_w   = (const float*)d_in[5];
  const float* cross_b   = (const float*)d_in[6];
  const float* crossfc_w = (const float*)d_in[7];
  const float* crossfc_b = (const float*)d_in[8];
  const float* vsdir_w   = (const float*)d_in[9];
  const float* vsdir_b   = (const float*)d_in[10];
  const float* vs_w      = (const float*)d_in[11];
  const float* vs_b      = (const float*)d_in[12];
  const float* ss_w      = (const float*)d_in[13];
  const float* ss_b      = (const float*)d_in[14];

  unsigned short* wsb = (unsigned short*)d_ws;
  float* wsf = (float*)((char*)d_ws + 204800);

  kprep0<<<16, 256, 0, stream>>>(weight, cross_w, crossfc_w, vsdir_w,
                                 cross_b, crossfc_b, vsdir_b, wsf);
  kprep1<<<64, 256, 0, stream>>>(weight, sv_w, cross_w, crossfc_w, vsdir_w,
                                 vs_w, ss_w, wsb, wsf);
  dim3 grid(4096/16, 8);
  kmain<<<grid, 256, 0, stream>>>(v_in, s_in, sv_b, vs_b, ss_b, wsb, wsf,
                                  (float*)d_out, (float*)d_out + VOUT_ELEMS);
}